// Round 3
// baseline (390.059 us; speedup 1.0000x reference)
//
#include <hip/hip_runtime.h>
#include <hip/hip_bf16.h>
#include <stdint.h>

#define DI __device__ __forceinline__

typedef __bf16 bf16x4 __attribute__((ext_vector_type(4)));
typedef __bf16 bf16x8 __attribute__((ext_vector_type(8)));
typedef float  f32x4  __attribute__((ext_vector_type(4)));

static constexpr int  BATCH = 4;
static constexpr int  SEQ   = 4096;
static constexpr int  DIM   = 768;
static constexpr long TOK   = (long)BATCH * SEQ;        // 16384
static constexpr int  QT    = SEQ / 128;                // 32 q-tiles per batch
static constexpr int  NTRI  = QT * (QT + 1) / 2;        // 528 causal 128x128 tiles
static constexpr float SCALE = 0.0360843918243516150f;  // 1/sqrt(768)

// ---------------- fp32 -> bf16 converts (merged launches) ----------------
__global__ void cvt3_kernel(const float* __restrict__ a, const float* __restrict__ b,
                            const float* __restrict__ c, __bf16* __restrict__ oa,
                            __bf16* __restrict__ ob, __bf16* __restrict__ oc, long n4){
  const float* in  = blockIdx.y == 0 ? a : blockIdx.y == 1 ? b : c;
  __bf16*      out = blockIdx.y == 0 ? oa : blockIdx.y == 1 ? ob : oc;
  long i = (long)blockIdx.x * blockDim.x + threadIdx.x;
  const long stride = (long)gridDim.x * blockDim.x;
  for(; i < n4; i += stride){
    float4 v = ((const float4*)in)[i];
    bf16x4 o = { (__bf16)v.x, (__bf16)v.y, (__bf16)v.z, (__bf16)v.w };
    ((bf16x4*)out)[i] = o;
  }
}
__global__ void cvt4_kernel(const float* __restrict__ a, const float* __restrict__ b,
                            const float* __restrict__ c, const float* __restrict__ d,
                            __bf16* __restrict__ oa, __bf16* __restrict__ ob,
                            __bf16* __restrict__ oc, __bf16* __restrict__ od, long n4){
  const float* in  = blockIdx.y == 0 ? a : blockIdx.y == 1 ? b : blockIdx.y == 2 ? c : d;
  __bf16*      out = blockIdx.y == 0 ? oa : blockIdx.y == 1 ? ob : blockIdx.y == 2 ? oc : od;
  long i = (long)blockIdx.x * blockDim.x + threadIdx.x;
  const long stride = (long)gridDim.x * blockDim.x;
  for(; i < n4; i += stride){
    float4 v = ((const float4*)in)[i];
    bf16x4 o = { (__bf16)v.x, (__bf16)v.y, (__bf16)v.z, (__bf16)v.w };
    ((bf16x4*)out)[i] = o;
  }
}

// ---------------- shared GEMM machinery ----------------
// LDS tile: [R rows][64 bf16 = 8 chunks of 16B], chunk XOR-swizzled by (row&7).
DI int swz_off(int r, int c){ return (r << 7) + ((c ^ (r & 7)) << 4); }

// Stage R x 64 bf16 tile (row-major, leading dim ld) via global_load_lds,
// pre-swizzled global source (m173), linear LDS dest. 512 threads.
template<int R>
DI void stage(const __bf16* __restrict__ src, long ld, char* lds, int tid){
  const int w = tid >> 6, l = tid & 63;
  const int rsub = l >> 3;
  const int kc   = (l & 7) ^ rsub;
  const __bf16* g = src + (long)(w * 8 + rsub) * ld + kc * 8;
  char* d = lds + (w << 10);
  #pragma unroll
  for(int i = 0; i < R / 64; ++i){
    __builtin_amdgcn_global_load_lds(
        (const __attribute__((address_space(1))) void*)(g + (long)(i * 64) * ld),
        (__attribute__((address_space(3))) void*)(d + i * 8192), 16, 0, 0);
  }
}

DI bf16x8 frag_ld(const char* lds, int row, int c){
  return *(const bf16x8*)(lds + swz_off(row, c));
}

// One MFMA cluster: 16 MFMAs (4x4 frags at k-half kk). Optional A row-sum (pv).
template<bool SUMA>
DI void mma_phase(const char* As, const char* Bs, int lane, int wr, int wc, int kk,
                  f32x4 acc[4][4], float* rs){
  const int c = kk * 4 + (lane >> 4);
  bf16x8 a[4], b[4];
  #pragma unroll
  for(int i = 0; i < 4; ++i) a[i] = frag_ld(As, wr + i * 16 + (lane & 15), c);
  #pragma unroll
  for(int j = 0; j < 4; ++j) b[j] = frag_ld(Bs, wc + j * 16 + (lane & 15), c);
  __builtin_amdgcn_s_setprio(1);
  #pragma unroll
  for(int i = 0; i < 4; ++i)
    #pragma unroll
    for(int j = 0; j < 4; ++j)
      acc[i][j] = __builtin_amdgcn_mfma_f32_16x16x32_bf16(a[i], b[j], acc[i][j], 0, 0, 0);
  __builtin_amdgcn_s_setprio(0);
  if(SUMA){
    #pragma unroll
    for(int i = 0; i < 4; ++i){
      float s = 0.f;
      #pragma unroll
      for(int e = 0; e < 8; ++e) s += (float)a[i][e];
      rs[i] += s;
    }
  }
}

// Pipelined K-loop: BM=128, BN=256, BK=64, 8 waves (2M x 4N), triple-buffered LDS,
// depth-2 prefetch with counted vmcnt (T3+T4), setprio around MFMA (T5).
// As: 3 x 16 KB, Bs: 3 x 32 KB.
template<bool SUM, class FA, class FB>
DI void kloop(FA fa, long lda, FB fb, long ldb, int nt, int tid,
              char* As, char* Bs, f32x4 acc[4][4], float* rs){
  const int lane = tid & 63, w = tid >> 6;
  const int wr = (w >> 2) * 64, wc = (w & 3) * 64;
  stage<128>(fa(0), lda, As, tid);
  stage<256>(fb(0), ldb, Bs, tid);
  if(nt > 1){
    stage<128>(fa(1), lda, As + 16384, tid);
    stage<256>(fb(1), ldb, Bs + 32768, tid);
  }
  int buf = 0;
  for(int t = 0; t < nt; ++t){
    // Wait for tile t's 6 loads only; tile t+1's 6 stay in flight (never vmcnt(0) mid-loop).
    if(t + 1 < nt) asm volatile("s_waitcnt vmcnt(6)" ::: "memory");
    else           asm volatile("s_waitcnt vmcnt(0)" ::: "memory");
    __builtin_amdgcn_s_barrier();
    const char* Ab = As + buf * 16384;
    const char* Bb = Bs + buf * 32768;
    const int pbuf = buf == 0 ? 2 : buf - 1;          // == (t+2) % 3
    const bool pf = (t + 2 < nt);
    if(pf) stage<128>(fa(t + 2), lda, As + pbuf * 16384, tid);
    if(SUM && wc == 0) mma_phase<true >(Ab, Bb, lane, wr, wc, 0, acc, rs);
    else               mma_phase<false>(Ab, Bb, lane, wr, wc, 0, acc, rs);
    if(pf) stage<256>(fb(t + 2), ldb, Bs + pbuf * 32768, tid);
    if(SUM && wc == 0) mma_phase<true >(Ab, Bb, lane, wr, wc, 1, acc, rs);
    else               mma_phase<false>(Ab, Bb, lane, wr, wc, 1, acc, rs);
    asm volatile("" ::: "memory");
    __builtin_amdgcn_s_barrier();                     // release buf before its re-stage
    buf = buf == 2 ? 0 : buf + 1;
  }
}

// Common bias+store epilogue (proj / oproj).
template<bool OUTF32>
DI void epi_store(f32x4 acc[4][4], const float* bias, bool biasm, void* C,
                  long m0, long n0, long ldc, int tid){
  const int lane = tid & 63, w = tid >> 6;
  const int wr = (w >> 2) * 64, wc = (w & 3) * 64;
  const int cl = lane & 15, rq = (lane >> 4) * 4;
  #pragma unroll
  for(int i = 0; i < 4; ++i)
    #pragma unroll
    for(int j = 0; j < 4; ++j){
      const long gc = n0 + wc + j * 16 + cl;
      #pragma unroll
      for(int e = 0; e < 4; ++e){
        const long gr = m0 + wr + i * 16 + rq + e;
        float v = acc[i][j][e] + bias[biasm ? gr : gc];
        if(OUTF32) ((float*)C)[gr * ldc + gc] = v;
        else       ((__bf16*)C)[gr * ldc + gc] = (__bf16)v;
      }
    }
}

// ---------------- fused Q/K/V projections (one dispatch, 3x384 blocks) ----------
__global__ __launch_bounds__(512)
void proj_qkv(const __bf16* __restrict__ xq, const __bf16* __restrict__ xk,
              const __bf16* __restrict__ xv, const __bf16* __restrict__ Wqb,
              const __bf16* __restrict__ Wkb, const __bf16* __restrict__ Wvb,
              const float* __restrict__ bq, const float* __restrict__ bk,
              const float* __restrict__ bv, __bf16* __restrict__ qb,
              __bf16* __restrict__ kb, __bf16* __restrict__ vbT){
  __shared__ __attribute__((aligned(128))) char As[49152];
  __shared__ __attribute__((aligned(128))) char Bs[98304];
  const int z = blockIdx.y, bid = blockIdx.x, tid = threadIdx.x;
  const __bf16 *A, *B; const float* bias; __bf16* C;
  long m0, n0, ldc; bool biasm;
  if(z == 0){ A = xq;  B = Wqb; bias = bq; C = qb;
              n0 = (bid % 3) * 256; m0 = (bid / 3) * 128; ldc = DIM; biasm = false; }
  else if(z == 1){ A = xk;  B = Wkb; bias = bk; C = kb;
              n0 = (bid % 3) * 256; m0 = (bid / 3) * 128; ldc = DIM; biasm = false; }
  else {      A = Wvb; B = xv;  bias = bv; C = vbT;
              n0 = (bid % 64) * 256; m0 = (bid / 64) * 128; ldc = TOK; biasm = true; }
  const __bf16* Ar = A + m0 * DIM;
  const __bf16* Br = B + n0 * DIM;
  f32x4 acc[4][4] = {};
  auto fa = [&](int t){ return Ar + t * 64; };
  auto fb = [&](int t){ return Br + t * 64; };
  kloop<false>(fa, DIM, fb, DIM, DIM / 64, tid, As, Bs, acc, nullptr);
  epi_store<false>(acc, bias, biasm, C, m0, n0, ldc, tid);
}

// ---------------- output projection -> fp32 d_out ----------------
__global__ __launch_bounds__(512)
void oproj(const __bf16* __restrict__ att, const __bf16* __restrict__ Wob,
           const float* __restrict__ bo, float* __restrict__ out){
  __shared__ __attribute__((aligned(128))) char As[49152];
  __shared__ __attribute__((aligned(128))) char Bs[98304];
  const int bid = blockIdx.x, tid = threadIdx.x;
  const long n0 = (bid % 3) * 256, m0 = (long)(bid / 3) * 128;
  const __bf16* Ar = att + m0 * DIM;
  const __bf16* Br = Wob + n0 * DIM;
  f32x4 acc[4][4] = {};
  auto fa = [&](int t){ return Ar + t * 64; };
  auto fb = [&](int t){ return Br + t * 64; };
  kloop<false>(fa, DIM, fb, DIM, DIM / 64, tid, As, Bs, acc, nullptr);
  epi_store<true>(acc, bo, false, out, m0, n0, DIM, tid);
}

// ---------------- QK^T: 128q x 256k tiles, fused exp -> compact bf16 P ----------
__global__ __launch_bounds__(512)
void qk_kernel(const __bf16* __restrict__ qb, const __bf16* __restrict__ kb,
               __bf16* __restrict__ Pc){
  __shared__ __attribute__((aligned(128))) char As[49152];
  __shared__ __attribute__((aligned(128))) char Bs[98304];
  const int b = blockIdx.y, t2 = blockIdx.x, tid = threadIdx.x;
  // decode t2 -> (qi 128-granular, Kp 256-granular k-pair), Kp <= qi>>1
  int m = (int)((sqrtf(4.0f * t2 + 1.0f) - 1.0f) * 0.5f);
  while((m + 1) * (m + 2) <= t2) ++m;
  while(m * (m + 1) > t2) --m;
  int qi, Kp;
  if(t2 < (m + 1) * (m + 1)){ qi = 2 * m;     Kp = t2 - m * (m + 1); }
  else                      { qi = 2 * m + 1; Kp = t2 - (m + 1) * (m + 1); }
  const __bf16* Aq = qb + ((long)b * SEQ + qi * 128) * DIM;
  const __bf16* Bk = kb + ((long)b * SEQ + Kp * 256) * DIM;
  f32x4 acc[4][4] = {};
  auto fa = [&](int t){ return Aq + t * 64; };
  auto fb = [&](int t){ return Bk + t * 64; };
  kloop<false>(fa, DIM, fb, DIM, DIM / 64, tid, As, Bs, acc, nullptr);

  const int lane = tid & 63, w = tid >> 6;
  const int wr = (w >> 2) * 64, wc = (w & 3) * 64;
  const int cl = lane & 15, rq = (lane >> 4) * 4;
  #pragma unroll
  for(int j = 0; j < 4; ++j){
    const int ki = 2 * Kp + ((wc + j * 16) >> 7);
    if(ki > qi) continue;                              // fully-masked tile: not stored
    const bool diag = (ki == qi);
    __bf16* tile = Pc + ((long)b * NTRI + (long)qi * (qi + 1) / 2 + ki) * 16384;
    const int kcol = ((wc + j * 16) & 127) + cl;
    #pragma unroll
    for(int i = 0; i < 4; ++i){
      #pragma unroll
      for(int e = 0; e < 4; ++e){
        const int rloc = wr + i * 16 + rq + e;
        float p = (diag && kcol > rloc) ? 0.0f
                  : __expf(fminf(acc[i][j][e] * SCALE, 30.0f));
        tile[rloc * 128 + kcol] = (__bf16)p;
      }
    }
  }
}

// ---------------- P.V GEMM with fused in-register row-sum ----------------
__global__ __launch_bounds__(512)
void pv_kernel(const __bf16* __restrict__ Pc, const __bf16* __restrict__ vbT,
               __bf16* __restrict__ att){
  __shared__ __attribute__((aligned(128))) char As[49152];
  __shared__ __attribute__((aligned(128))) char Bs[98304];
  __shared__ float sInv[128];
  const int b = blockIdx.z, qi = 31 - blockIdx.y, tid = threadIdx.x;  // long-K first
  const long n0 = (long)blockIdx.x * 256;
  const __bf16* Pq = Pc + ((long)b * NTRI + (long)qi * (qi + 1) / 2) * 16384;
  const __bf16* Bv = vbT + n0 * TOK + (long)b * SEQ;
  f32x4 acc[4][4] = {};
  float rs[4] = {0.f, 0.f, 0.f, 0.f};
  auto fa = [&](int t){ return Pq + (long)(t >> 1) * 16384 + (t & 1) * 64; };
  auto fb = [&](int t){ return Bv + t * 64; };
  kloop<true>(fa, 128, fb, TOK, 2 * (qi + 1), tid, As, Bs, acc, rs);

  const int lane = tid & 63, w = tid >> 6;
  const int wr = (w >> 2) * 64, wc = (w & 3) * 64;
  if(wc == 0){                                        // waves 0,4 hold full row sums
    #pragma unroll
    for(int i = 0; i < 4; ++i){
      float s = rs[i];
      s += __shfl_xor(s, 16);
      s += __shfl_xor(s, 32);
      if(lane < 16) sInv[wr + i * 16 + lane] = 1.0f / s;
    }
  }
  __syncthreads();
  const int cl = lane & 15, rq = (lane >> 4) * 4;
  #pragma unroll
  for(int i = 0; i < 4; ++i)
    #pragma unroll
    for(int j = 0; j < 4; ++j){
      const long gc = n0 + wc + j * 16 + cl;
      #pragma unroll
      for(int e = 0; e < 4; ++e){
        const int rloc = wr + i * 16 + rq + e;
        float v = acc[i][j][e] * sInv[rloc];
        att[((long)b * SEQ + qi * 128 + rloc) * DIM + gc] = (__bf16)v;
      }
    }
}

// ---------------- launch ----------------
extern "C" void kernel_launch(void* const* d_in, const int* in_sizes, int n_in,
                              void* d_out, int out_size, void* d_ws, size_t ws_size,
                              hipStream_t stream){
  const float* query = (const float*)d_in[0];
  const float* key_  = (const float*)d_in[1];
  const float* value = (const float*)d_in[2];
  const float* Wq = (const float*)d_in[3];
  const float* bq = (const float*)d_in[4];
  const float* Wk = (const float*)d_in[5];
  const float* bk = (const float*)d_in[6];
  const float* Wv = (const float*)d_in[7];
  const float* bv = (const float*)d_in[8];
  const float* Wo = (const float*)d_in[9];
  const float* bo = (const float*)d_in[10];
  // d_in[11]: causal tril mask — implemented structurally (block-triangular P).

  char* p = (char*)d_ws;
  auto carve = [&](size_t bytes)->char*{
    char* r = p; p += (bytes + 255) & ~(size_t)255; return r;
  };
  const size_t tb = (size_t)TOK * DIM * 2;   // 25.2 MB
  __bf16* xq  = (__bf16*)carve(tb);
  __bf16* xk  = (__bf16*)carve(tb);
  __bf16* xv  = (__bf16*)carve(tb);
  __bf16* qb  = (__bf16*)carve(tb);
  __bf16* kb  = (__bf16*)carve(tb);
  __bf16* vbT = (__bf16*)carve(tb);
  __bf16* Wqb = (__bf16*)carve((size_t)DIM * DIM * 2);
  __bf16* Wkb = (__bf16*)carve((size_t)DIM * DIM * 2);
  __bf16* Wvb = (__bf16*)carve((size_t)DIM * DIM * 2);
  __bf16* Wob = (__bf16*)carve((size_t)DIM * DIM * 2);
  __bf16* Pc  = (__bf16*)carve((size_t)BATCH * NTRI * 16384 * 2);  // 69.2 MB
  __bf16* att = xq;                           // xq dead after q-projection
  if((size_t)(p - (char*)d_ws) > ws_size) return;

  const long nIn4 = TOK * DIM / 4, nW4 = (long)DIM * DIM / 4;
  dim3 g3(2048, 3), g4((unsigned)((nW4 + 255) / 256), 4);
  cvt3_kernel<<<g3, 256, 0, stream>>>(query, key_, value, xq, xk, xv, nIn4);
  cvt4_kernel<<<g4, 256, 0, stream>>>(Wq, Wk, Wv, Wo, Wqb, Wkb, Wvb, Wob, nW4);

  // Q, K, V^T projections in one dispatch (1152 blocks)
  proj_qkv<<<dim3(384, 3), 512, 0, stream>>>(xq, xk, xv, Wqb, Wkb, Wvb,
                                             bq, bk, bv, qb, kb, vbT);

  qk_kernel<<<dim3(272, BATCH), 512, 0, stream>>>(qb, kb, Pc);

  pv_kernel<<<dim3(3, QT, BATCH), 512, 0, stream>>>(Pc, vbT, att);

  oproj<<<384, 512, 0, stream>>>(att, Wob, bo, (float*)d_out);
}

// Round 5
// 381.262 us; speedup vs baseline: 1.0231x; 1.0231x over previous
//
#include <hip/hip_runtime.h>
#include <hip/hip_bf16.h>
#include <stdint.h>

#define DI __device__ __forceinline__

typedef __bf16 bf16x4 __attribute__((ext_vector_type(4)));
typedef __bf16 bf16x8 __attribute__((ext_vector_type(8)));
typedef float  f32x4  __attribute__((ext_vector_type(4)));

static constexpr int  BATCH = 4;
static constexpr int  SEQ   = 4096;
static constexpr int  DIM   = 768;
static constexpr long TOK   = (long)BATCH * SEQ;        // 16384
static constexpr int  QT    = SEQ / 128;                // 32 q-tiles per batch
static constexpr int  NTRI  = QT * (QT + 1) / 2;        // 528 causal 128x128 tiles
static constexpr float SCALE = 0.0360843918243516150f;  // 1/sqrt(768)

// ---------------- fp32 -> bf16 converts (merged launches) ----------------
__global__ void cvt3_kernel(const float* __restrict__ a, const float* __restrict__ b,
                            const float* __restrict__ c, __bf16* __restrict__ oa,
                            __bf16* __restrict__ ob, __bf16* __restrict__ oc, long n4){
  const float* in  = blockIdx.y == 0 ? a : blockIdx.y == 1 ? b : c;
  __bf16*      out = blockIdx.y == 0 ? oa : blockIdx.y == 1 ? ob : oc;
  long i = (long)blockIdx.x * blockDim.x + threadIdx.x;
  const long stride = (long)gridDim.x * blockDim.x;
  for(; i < n4; i += stride){
    float4 v = ((const float4*)in)[i];
    bf16x4 o = { (__bf16)v.x, (__bf16)v.y, (__bf16)v.z, (__bf16)v.w };
    ((bf16x4*)out)[i] = o;
  }
}
__global__ void cvt4_kernel(const float* __restrict__ a, const float* __restrict__ b,
                            const float* __restrict__ c, const float* __restrict__ d,
                            __bf16* __restrict__ oa, __bf16* __restrict__ ob,
                            __bf16* __restrict__ oc, __bf16* __restrict__ od, long n4){
  const float* in  = blockIdx.y == 0 ? a : blockIdx.y == 1 ? b : blockIdx.y == 2 ? c : d;
  __bf16*      out = blockIdx.y == 0 ? oa : blockIdx.y == 1 ? ob : blockIdx.y == 2 ? oc : od;
  long i = (long)blockIdx.x * blockDim.x + threadIdx.x;
  const long stride = (long)gridDim.x * blockDim.x;
  for(; i < n4; i += stride){
    float4 v = ((const float4*)in)[i];
    bf16x4 o = { (__bf16)v.x, (__bf16)v.y, (__bf16)v.z, (__bf16)v.w };
    ((bf16x4*)out)[i] = o;
  }
}

// ================= round-2 proven 128x256 core (pv / oproj) =================
// LDS tile: [R rows][64 bf16 = 8 chunks of 16B], chunk XOR-swizzled by (row&7).
DI int swz_off(int r, int c){ return (r << 7) + ((c ^ (r & 7)) << 4); }

template<int R>
DI void stage(const __bf16* __restrict__ src, long ld, char* lds, int tid){
  const int w = tid >> 6, l = tid & 63;
  const int rsub = l >> 3;
  const int kc   = (l & 7) ^ rsub;
  const __bf16* g = src + (long)(w * 8 + rsub) * ld + kc * 8;
  char* d = lds + (w << 10);
  #pragma unroll
  for(int i = 0; i < R / 64; ++i){
    __builtin_amdgcn_global_load_lds(
        (const __attribute__((address_space(1))) void*)(g + (long)(i * 64) * ld),
        (__attribute__((address_space(3))) void*)(d + i * 8192), 16, 0, 0);
  }
}

DI bf16x8 frag_ld(const char* lds, int row, int c){
  return *(const bf16x8*)(lds + swz_off(row, c));
}

template<bool SUMA>
DI void mma_phase(const char* As, const char* Bs, int lane, int wr, int wc, int kk,
                  f32x4 acc[4][4], float* rs){
  const int c = kk * 4 + (lane >> 4);
  bf16x8 a[4], b[4];
  #pragma unroll
  for(int i = 0; i < 4; ++i) a[i] = frag_ld(As, wr + i * 16 + (lane & 15), c);
  #pragma unroll
  for(int j = 0; j < 4; ++j) b[j] = frag_ld(Bs, wc + j * 16 + (lane & 15), c);
  __builtin_amdgcn_s_setprio(1);
  #pragma unroll
  for(int i = 0; i < 4; ++i)
    #pragma unroll
    for(int j = 0; j < 4; ++j)
      acc[i][j] = __builtin_amdgcn_mfma_f32_16x16x32_bf16(a[i], b[j], acc[i][j], 0, 0, 0);
  __builtin_amdgcn_s_setprio(0);
  if(SUMA){
    #pragma unroll
    for(int i = 0; i < 4; ++i){
      float s = 0.f;
      #pragma unroll
      for(int e = 0; e < 8; ++e) s += (float)a[i][e];
      rs[i] += s;
    }
  }
}

// Single-buffered K-loop (round-2 proven, 48KB LDS -> 3 blocks/CU).
template<bool SUM, class FA, class FB>
DI void kloop2(FA fa, long lda, FB fb, long ldb, int nt, int tid,
               char* As, char* Bs, f32x4 acc[4][4], float* rs){
  const int lane = tid & 63, w = tid >> 6;
  const int wr = (w >> 2) * 64, wc = (w & 3) * 64;
  for(int t = 0; t < nt; ++t){
    stage<128>(fa(t), lda, As, tid);
    stage<256>(fb(t), ldb, Bs, tid);
    __syncthreads();
    if(SUM && wc == 0){
      mma_phase<true >(As, Bs, lane, wr, wc, 0, acc, rs);
      mma_phase<true >(As, Bs, lane, wr, wc, 1, acc, rs);
    } else {
      mma_phase<false>(As, Bs, lane, wr, wc, 0, acc, rs);
      mma_phase<false>(As, Bs, lane, wr, wc, 1, acc, rs);
    }
    __syncthreads();
  }
}

// ================= m201-style 256x256 8-phase core (proj / qk) =================
// LDS 128KB: A region [2 slot][2 kk][256 rows][32 cols], B region same at +64KB.
// Within a kk-slab: row stride 64B, 4 chunks of 16B, phys chunk = c ^ ((row>>1)&3).
DI void issue_unit(const __bf16* __restrict__ src, long ld, char* slab, int tid){
  const int w = tid >> 6, lane = tid & 63;
  #pragma unroll
  for(int r = 0; r < 2; ++r){
    const int row = w * 16 + (lane >> 2) + r * 128;
    const int c   = (lane & 3) ^ ((row >> 1) & 3);
    const __bf16* g = src + (long)row * ld + c * 8;
    __builtin_amdgcn_global_load_lds(
        (const __attribute__((address_space(1))) void*)g,
        (__attribute__((address_space(3))) void*)(slab + w * 1024 + r * 8192), 16, 0, 0);
  }
}

template<int G>
DI void mma16(f32x4 (&acc)[8][4], const bf16x8 (&a)[4], const bf16x8 (&b)[4]){
  __builtin_amdgcn_s_setprio(1);
  #pragma unroll
  for(int i = 0; i < 4; ++i)
    #pragma unroll
    for(int j = 0; j < 4; ++j)
      acc[G * 4 + i][j] =
          __builtin_amdgcn_mfma_f32_16x16x32_bf16(a[i], b[j], acc[G * 4 + i][j], 0, 0, 0);
  __builtin_amdgcn_s_setprio(0);
}
template<int G>
DI void rdA(bf16x8 (&a)[4], const char* LA, int sbase, const int (&offA)[8]){
  #pragma unroll
  for(int i = 0; i < 4; ++i) a[i] = *(const bf16x8*)(LA + sbase + offA[G * 4 + i]);
}
DI void rdB(bf16x8 (&b)[4], const char* LB, int sbase, const int (&offB)[4]){
  #pragma unroll
  for(int j = 0; j < 4; ++j) b[j] = *(const bf16x8*)(LB + sbase + offB[j]);
}
#define VMW(N) asm volatile("s_waitcnt vmcnt(" #N ")" ::: "memory")

// BM=BN=256, BK=64, 8 waves (2Mx4N, wave tile 128x64). nt must be even.
// Unit = kk-slab (256x32, 2 loads/thread). Issue->consume gap 5-6 phases;
// barriers at odd phases only; vmcnt(8) counted (never 0 mid-loop).
// Per-iteration issue stream: A11,B11 | A00,B00 | A01,B01 | A10,B10 — each
// VMW(8) completes exactly the 2 units consumed in the following phase-pair.
template<class FA, class FB>
DI void kloop8(FA fa, long lda, FB fb, long ldb, int nt, int tid,
               char* L, f32x4 (&acc)[8][4]){
  const int lane = tid & 63, w = tid >> 6;
  int offA[8], offB[4];
  #pragma unroll
  for(int i = 0; i < 8; ++i){
    const int r = (w >> 2) * 128 + i * 16 + (lane & 15);
    offA[i] = r * 64 + ((((lane >> 4)) ^ ((r >> 1) & 3)) << 4);
  }
  #pragma unroll
  for(int j = 0; j < 4; ++j){
    const int r = (w & 3) * 64 + j * 16 + (lane & 15);
    offB[j] = r * 64 + ((((lane >> 4)) ^ ((r >> 1) & 3)) << 4);
  }
  char* LA = L;
  char* LB = L + 65536;
  auto AS = [](int s, int k){ return s * 32768 + k * 16384; };
  // prologue: 6 units = 12 loads/thread
  issue_unit(fa(0),      lda, LA + AS(0, 0), tid);
  issue_unit(fb(0),      ldb, LB + AS(0, 0), tid);
  issue_unit(fa(0) + 32, lda, LA + AS(0, 1), tid);
  issue_unit(fb(0) + 32, ldb, LB + AS(0, 1), tid);
  issue_unit(fa(1),      lda, LA + AS(1, 0), tid);
  issue_unit(fb(1),      ldb, LB + AS(1, 0), tid);
  bf16x8 a[4], b[4];
  for(int t = 0; t < nt; t += 2){
    const bool more = (t + 2 < nt);
    // ---- tile t (slot 0) ----
    VMW(8); __builtin_amdgcn_s_barrier();                       // ph1
    issue_unit(fa(t + 1) + 32, lda, LA + AS(1, 1), tid);
    rdB(b, LB, AS(0, 0), offB);
    rdA<0>(a, LA, AS(0, 0), offA);  mma16<0>(acc, a, b);
    issue_unit(fb(t + 1) + 32, ldb, LB + AS(1, 1), tid);        // ph2
    rdA<1>(a, LA, AS(0, 0), offA);  mma16<1>(acc, a, b);
    VMW(8); __builtin_amdgcn_s_barrier();                       // ph3
    if(more) issue_unit(fa(t + 2), lda, LA + AS(0, 0), tid);
    rdB(b, LB, AS(0, 1), offB);
    rdA<0>(a, LA, AS(0, 1), offA);  mma16<0>(acc, a, b);
    if(more) issue_unit(fb(t + 2), ldb, LB + AS(0, 0), tid);    // ph4
    rdA<1>(a, LA, AS(0, 1), offA);  mma16<1>(acc, a, b);
    // ---- tile t+1 (slot 1) ----
    if(more){ VMW(8); } else { VMW(4); }                        // ph5
    __builtin_amdgcn_s_barrier();
    if(more) issue_unit(fa(t + 2) + 32, lda, LA + AS(0, 1), tid);
    rdB(b, LB, AS(1, 0), offB);
    rdA<0>(a, LA, AS(1, 0), offA);  mma16<0>(acc, a, b);
    if(more) issue_unit(fb(t + 2) + 32, ldb, LB + AS(0, 1), tid); // ph6
    rdA<1>(a, LA, AS(1, 0), offA);  mma16<1>(acc, a, b);
    if(more){ VMW(8); } else { VMW(0); }                        // ph7
    __builtin_amdgcn_s_barrier();
    if(more) issue_unit(fa(t + 3), lda, LA + AS(1, 0), tid);
    rdB(b, LB, AS(1, 1), offB);
    rdA<0>(a, LA, AS(1, 1), offA);  mma16<0>(acc, a, b);
    if(more) issue_unit(fb(t + 3), ldb, LB + AS(1, 0), tid);    // ph8 (FIX: was AS(1,1))
    rdA<1>(a, LA, AS(1, 1), offA);  mma16<1>(acc, a, b);
  }
}

// bijective XCD swizzle (grid divisible by 8)
DI int xcd_swz(int bid, int n){ const int c = n >> 3; return (bid & 7) * c + (bid >> 3); }

// ---------------- fused Q/K/V projections: 256^2 8-phase ----------------
__global__ __launch_bounds__(512, 2)
void proj_qkv(const __bf16* __restrict__ xq, const __bf16* __restrict__ xk,
              const __bf16* __restrict__ xv, const __bf16* __restrict__ Wqb,
              const __bf16* __restrict__ Wkb, const __bf16* __restrict__ Wvb,
              const float* __restrict__ bq, const float* __restrict__ bk,
              const float* __restrict__ bv, __bf16* __restrict__ qb,
              __bf16* __restrict__ kb, __bf16* __restrict__ vbT){
  __shared__ __attribute__((aligned(128))) char L[131072];
  const int z = blockIdx.y, tid = threadIdx.x;
  const int bid = xcd_swz(blockIdx.x, 192);
  const __bf16 *A, *B; const float* bias; __bf16* C;
  long m0, n0, ldc; bool biasm;
  if(z == 0){ A = xq;  B = Wqb; bias = bq; C = qb;
              m0 = (long)(bid / 3) * 256; n0 = (bid % 3) * 256; ldc = DIM; biasm = false; }
  else if(z == 1){ A = xk;  B = Wkb; bias = bk; C = kb;
              m0 = (long)(bid / 3) * 256; n0 = (bid % 3) * 256; ldc = DIM; biasm = false; }
  else {      A = Wvb; B = xv;  bias = bv; C = vbT;
              m0 = (long)(bid / 64) * 256; n0 = (bid % 64) * 256; ldc = TOK; biasm = true; }
  const __bf16* Ar = A + m0 * DIM;
  const __bf16* Br = B + n0 * DIM;
  f32x4 acc[8][4] = {};
  auto fa = [&](int t){ return Ar + t * 64; };
  auto fb = [&](int t){ return Br + t * 64; };
  kloop8(fa, DIM, fb, DIM, DIM / 64, tid, L, acc);

  const int lane = tid & 63, w = tid >> 6;
  const int cl = lane & 15, rq = (lane >> 4) * 4;
  #pragma unroll
  for(int i = 0; i < 8; ++i)
    #pragma unroll
    for(int j = 0; j < 4; ++j){
      const long gc = n0 + (w & 3) * 64 + j * 16 + cl;
      #pragma unroll
      for(int e = 0; e < 4; ++e){
        const long gr = m0 + (w >> 2) * 128 + i * 16 + rq + e;
        C[gr * ldc + gc] = (__bf16)(acc[i][j][e] + bias[biasm ? gr : gc]);
      }
    }
}

// ---------------- QK^T: 256x256 causal tiles, 8-phase, fused exp ----------------
__global__ __launch_bounds__(512, 2)
void qk_kernel(const __bf16* __restrict__ qb, const __bf16* __restrict__ kb,
               __bf16* __restrict__ Pc){
  __shared__ __attribute__((aligned(128))) char L[131072];
  const int b = blockIdx.y, tid = threadIdx.x;
  const int t = xcd_swz(blockIdx.x, 136);             // 0..135 tri tile id
  int Qi = (int)((sqrtf(8.0f * t + 1.0f) - 1.0f) * 0.5f);
  while((Qi + 1) * (Qi + 2) / 2 <= t) Qi++;
  while(Qi * (Qi + 1) / 2 > t) Qi--;
  const int Ki = t - Qi * (Qi + 1) / 2;
  const __bf16* Aq = qb + ((long)b * SEQ + Qi * 256) * DIM;
  const __bf16* Bk = kb + ((long)b * SEQ + Ki * 256) * DIM;
  f32x4 acc[8][4] = {};
  auto fa = [&](int t_){ return Aq + t_ * 64; };
  auto fb = [&](int t_){ return Bk + t_ * 64; };
  kloop8(fa, DIM, fb, DIM, DIM / 64, tid, L, acc);

  const int lane = tid & 63, w = tid >> 6;
  const int cl = lane & 15, rq = (lane >> 4) * 4;
  const int qi = 2 * Qi + (w >> 2);                   // wave's 128-row strip
  #pragma unroll
  for(int j = 0; j < 4; ++j){
    const int kw = (w & 3) * 64 + j * 16;
    const int ki = 2 * Ki + (kw >> 7);
    if(ki > qi) continue;                             // fully-masked subtile
    const bool diag = (ki == qi);
    __bf16* tile = Pc + ((long)b * NTRI + (long)qi * (qi + 1) / 2 + ki) * 16384;
    const int kcol = (kw & 127) + cl;
    #pragma unroll
    for(int i = 0; i < 8; ++i){
      #pragma unroll
      for(int e = 0; e < 4; ++e){
        const int rloc = i * 16 + rq + e;
        float p = (diag && kcol > rloc) ? 0.0f
                  : __expf(fminf(acc[i][j][e] * SCALE, 30.0f));
        tile[rloc * 128 + kcol] = (__bf16)p;
      }
    }
  }
}

// ---------------- P.V GEMM (round-2 core) with fused in-register row-sum ----------
__global__ __launch_bounds__(512)
void pv_kernel(const __bf16* __restrict__ Pc, const __bf16* __restrict__ vbT,
               __bf16* __restrict__ att){
  __shared__ __attribute__((aligned(128))) char As[16384];
  __shared__ __attribute__((aligned(128))) char Bs[32768];
  __shared__ float sInv[128];
  const int b = blockIdx.z, qi = 31 - blockIdx.y, tid = threadIdx.x;  // long-K first
  const long n0 = (long)blockIdx.x * 256;
  const __bf16* Pq = Pc + ((long)b * NTRI + (long)qi * (qi + 1) / 2) * 16384;
  const __bf16* Bv = vbT + n0 * TOK + (long)b * SEQ;
  f32x4 acc[4][4] = {};
  float rs[4] = {0.f, 0.f, 0.f, 0.f};
  auto fa = [&](int t){ return Pq + (long)(t >> 1) * 16384 + (t & 1) * 64; };
  auto fb = [&](int t){ return Bv + t * 64; };
  kloop2<true>(fa, 128, fb, TOK, 2 * (qi + 1), tid, As, Bs, acc, rs);

  const int lane = tid & 63, w = tid >> 6;
  const int wr = (w >> 2) * 64, wc = (w & 3) * 64;
  if(wc == 0){                                        // waves 0,4 hold full row sums
    #pragma unroll
    for(int i = 0; i < 4; ++i){
      float s = rs[i];
      s += __shfl_xor(s, 16);
      s += __shfl_xor(s, 32);
      if(lane < 16) sInv[wr + i * 16 + lane] = 1.0f / s;
    }
  }
  __syncthreads();
  const int cl = lane & 15, rq = (lane >> 4) * 4;
  #pragma unroll
  for(int i = 0; i < 4; ++i)
    #pragma unroll
    for(int j = 0; j < 4; ++j){
      const long gc = n0 + wc + j * 16 + cl;
      #pragma unroll
      for(int e = 0; e < 4; ++e){
        const int rloc = wr + i * 16 + rq + e;
        float v = acc[i][j][e] * sInv[rloc];
        att[((long)b * SEQ + qi * 128 + rloc) * DIM + gc] = (__bf16)v;
      }
    }
}

// ---------------- output projection (round-2 core) -> fp32 d_out ----------------
__global__ __launch_bounds__(512)
void oproj(const __bf16* __restrict__ att, const __bf16* __restrict__ Wob,
           const float* __restrict__ bo, float* __restrict__ out){
  __shared__ __attribute__((aligned(128))) char As[16384];
  __shared__ __attribute__((aligned(128))) char Bs[32768];
  const int bid = blockIdx.x, tid = threadIdx.x;
  const long n0 = (bid % 3) * 256, m0 = (long)(bid / 3) * 128;
  const __bf16* Ar = att + m0 * DIM;
  const __bf16* Br = Wob + n0 * DIM;
  f32x4 acc[4][4] = {};
  auto fa = [&](int t){ return Ar + t * 64; };
  auto fb = [&](int t){ return Br + t * 64; };
  kloop2<false>(fa, DIM, fb, DIM, DIM / 64, tid, As, Bs, acc, nullptr);
  const int lane = tid & 63, w = tid >> 6;
  const int wr = (w >> 2) * 64, wc = (w & 3) * 64;
  const int cl = lane & 15, rq = (lane >> 4) * 4;
  #pragma unroll
  for(int i = 0; i < 4; ++i)
    #pragma unroll
    for(int j = 0; j < 4; ++j){
      const long gc = n0 + wc + j * 16 + cl;
      #pragma unroll
      for(int e = 0; e < 4; ++e){
        const long gr = m0 + wr + i * 16 + rq + e;
        out[gr * DIM + gc] = acc[i][j][e] + bo[gc];
      }
    }
}

// ---------------- launch ----------------
extern "C" void kernel_launch(void* const* d_in, const int* in_sizes, int n_in,
                              void* d_out, int out_size, void* d_ws, size_t ws_size,
                              hipStream_t stream){
  const float* query = (const float*)d_in[0];
  const float* key_  = (const float*)d_in[1];
  const float* value = (const float*)d_in[2];
  const float* Wq = (const float*)d_in[3];
  const float* bq = (const float*)d_in[4];
  const float* Wk = (const float*)d_in[5];
  const float* bk = (const float*)d_in[6];
  const float* Wv = (const float*)d_in[7];
  const float* bv = (const float*)d_in[8];
  const float* Wo = (const float*)d_in[9];
  const float* bo = (const float*)d_in[10];
  // d_in[11]: causal tril mask — implemented structurally (block-triangular P).

  char* p = (char*)d_ws;
  auto carve = [&](size_t bytes)->char*{
    char* r = p; p += (bytes + 255) & ~(size_t)255; return r;
  };
  const size_t tb = (size_t)TOK * DIM * 2;   // 25.2 MB
  __bf16* xq  = (__bf16*)carve(tb);
  __bf16* xk  = (__bf16*)carve(tb);
  __bf16* xv  = (__bf16*)carve(tb);
  __bf16* qb  = (__bf16*)carve(tb);
  __bf16* kb  = (__bf16*)carve(tb);
  __bf16* vbT = (__bf16*)carve(tb);
  __bf16* Wqb = (__bf16*)carve((size_t)DIM * DIM * 2);
  __bf16* Wkb = (__bf16*)carve((size_t)DIM * DIM * 2);
  __bf16* Wvb = (__bf16*)carve((size_t)DIM * DIM * 2);
  __bf16* Wob = (__bf16*)carve((size_t)DIM * DIM * 2);
  __bf16* Pc  = (__bf16*)carve((size_t)BATCH * NTRI * 16384 * 2);  // 69.2 MB
  __bf16* att = xq;                           // xq dead after q-projection
  if((size_t)(p - (char*)d_ws) > ws_size) return;

  const long nIn4 = TOK * DIM / 4, nW4 = (long)DIM * DIM / 4;
  dim3 g3(2048, 3), g4((unsigned)((nW4 + 255) / 256), 4);
  cvt3_kernel<<<g3, 256, 0, stream>>>(query, key_, value, xq, xk, xv, nIn4);
  cvt4_kernel<<<g4, 256, 0, stream>>>(Wq, Wk, Wv, Wo, Wqb, Wkb, Wvb, Wob, nW4);

  // Q, K, V^T projections: 256^2 8-phase, one dispatch (576 blocks)
  proj_qkv<<<dim3(192, 3), 512, 0, stream>>>(xq, xk, xv, Wqb, Wkb, Wvb,
                                             bq, bk, bv, qb, kb, vbT);

  // QK^T: 256^2 causal tiles (136 per batch), 8-phase
  qk_kernel<<<dim3(136, BATCH), 512, 0, stream>>>(qb, kb, Pc);

  pv_kernel<<<dim3(3, QT, BATCH), 512, 0, stream>>>(Pc, vbT, att);

  oproj<<<384, 512, 0, stream>>>(att, Wob, bo, (float*)d_out);
}

// Round 6
// 339.754 us; speedup vs baseline: 1.1481x; 1.1222x over previous
//
#include <hip/hip_runtime.h>
#include <hip/hip_bf16.h>
#include <stdint.h>

#define DI __device__ __forceinline__

typedef __bf16 bf16x4 __attribute__((ext_vector_type(4)));
typedef __bf16 bf16x8 __attribute__((ext_vector_type(8)));
typedef float  f32x4  __attribute__((ext_vector_type(4)));

static constexpr int  BATCH = 4;
static constexpr int  SEQ   = 4096;
static constexpr int  DIM   = 768;
static constexpr long TOK   = (long)BATCH * SEQ;        // 16384
static constexpr int  QT    = SEQ / 128;                // 32 q-tiles per batch
static constexpr int  NTRI  = QT * (QT + 1) / 2;        // 528 causal 128x128 tiles
static constexpr float SCALE = 0.0360843918243516150f;  // 1/sqrt(768)

// ---------------- fp32 -> bf16 converts (merged launches) ----------------
__global__ void cvt3_kernel(const float* __restrict__ a, const float* __restrict__ b,
                            const float* __restrict__ c, __bf16* __restrict__ oa,
                            __bf16* __restrict__ ob, __bf16* __restrict__ oc, long n4){
  const float* in  = blockIdx.y == 0 ? a : blockIdx.y == 1 ? b : c;
  __bf16*      out = blockIdx.y == 0 ? oa : blockIdx.y == 1 ? ob : oc;
  long i = (long)blockIdx.x * blockDim.x + threadIdx.x;
  const long stride = (long)gridDim.x * blockDim.x;
  for(; i < n4; i += stride){
    float4 v = ((const float4*)in)[i];
    bf16x4 o = { (__bf16)v.x, (__bf16)v.y, (__bf16)v.z, (__bf16)v.w };
    ((bf16x4*)out)[i] = o;
  }
}
__global__ void cvt4_kernel(const float* __restrict__ a, const float* __restrict__ b,
                            const float* __restrict__ c, const float* __restrict__ d,
                            __bf16* __restrict__ oa, __bf16* __restrict__ ob,
                            __bf16* __restrict__ oc, __bf16* __restrict__ od, long n4){
  const float* in  = blockIdx.y == 0 ? a : blockIdx.y == 1 ? b : blockIdx.y == 2 ? c : d;
  __bf16*      out = blockIdx.y == 0 ? oa : blockIdx.y == 1 ? ob : blockIdx.y == 2 ? oc : od;
  long i = (long)blockIdx.x * blockDim.x + threadIdx.x;
  const long stride = (long)gridDim.x * blockDim.x;
  for(; i < n4; i += stride){
    float4 v = ((const float4*)in)[i];
    bf16x4 o = { (__bf16)v.x, (__bf16)v.y, (__bf16)v.z, (__bf16)v.w };
    ((bf16x4*)out)[i] = o;
  }
}

// ================= round-2 proven 128x256 core (pv / oproj) =================
// LDS tile: [R rows][64 bf16 = 8 chunks of 16B], chunk XOR-swizzled by (row&7).
DI int swz_off(int r, int c){ return (r << 7) + ((c ^ (r & 7)) << 4); }

template<int R>
DI void stage(const __bf16* __restrict__ src, long ld, char* lds, int tid){
  const int w = tid >> 6, l = tid & 63;
  const int rsub = l >> 3;
  const int kc   = (l & 7) ^ rsub;
  const __bf16* g = src + (long)(w * 8 + rsub) * ld + kc * 8;
  char* d = lds + (w << 10);
  #pragma unroll
  for(int i = 0; i < R / 64; ++i){
    __builtin_amdgcn_global_load_lds(
        (const __attribute__((address_space(1))) void*)(g + (long)(i * 64) * ld),
        (__attribute__((address_space(3))) void*)(d + i * 8192), 16, 0, 0);
  }
}

DI bf16x8 frag_ld(const char* lds, int row, int c){
  return *(const bf16x8*)(lds + swz_off(row, c));
}

// One K=64 step: 32 MFMAs per wave (4x4 frags x 2 k-halves). No setprio (m190:
// setprio is null-to-negative on lockstep 2-phase loops), no fused row-sum
// (round-3/5 regression isolated to these two additions).
DI void mma_tile(const char* As, const char* Bs, int lane, int wr, int wc, f32x4 acc[4][4]){
  #pragma unroll
  for(int kk = 0; kk < 2; ++kk){
    const int c = kk * 4 + (lane >> 4);
    bf16x8 a[4], b[4];
    #pragma unroll
    for(int i = 0; i < 4; ++i) a[i] = frag_ld(As, wr + i * 16 + (lane & 15), c);
    #pragma unroll
    for(int j = 0; j < 4; ++j) b[j] = frag_ld(Bs, wc + j * 16 + (lane & 15), c);
    #pragma unroll
    for(int i = 0; i < 4; ++i)
      #pragma unroll
      for(int j = 0; j < 4; ++j)
        acc[i][j] = __builtin_amdgcn_mfma_f32_16x16x32_bf16(a[i], b[j], acc[i][j], 0, 0, 0);
  }
}

// Single-buffered K-loop (round-2 proven, 48KB LDS -> 3 blocks/CU).
template<class FA, class FB>
DI void kloop2(FA fa, long lda, FB fb, long ldb, int nt, int tid,
               char* As, char* Bs, f32x4 acc[4][4]){
  const int lane = tid & 63, w = tid >> 6;
  const int wr = (w >> 2) * 64, wc = (w & 3) * 64;
  for(int t = 0; t < nt; ++t){
    stage<128>(fa(t), lda, As, tid);
    stage<256>(fb(t), ldb, Bs, tid);
    __syncthreads();
    mma_tile(As, Bs, lane, wr, wc, acc);
    __syncthreads();
  }
}

// ================= m201-style 256x256 8-phase core (proj / qk) =================
// LDS 128KB: A region [2 slot][2 kk][256 rows][32 cols], B region same at +64KB.
// Within a kk-slab: row stride 64B, 4 chunks of 16B, phys chunk = c ^ ((row>>1)&3).
DI void issue_unit(const __bf16* __restrict__ src, long ld, char* slab, int tid){
  const int w = tid >> 6, lane = tid & 63;
  #pragma unroll
  for(int r = 0; r < 2; ++r){
    const int row = w * 16 + (lane >> 2) + r * 128;
    const int c   = (lane & 3) ^ ((row >> 1) & 3);
    const __bf16* g = src + (long)row * ld + c * 8;
    __builtin_amdgcn_global_load_lds(
        (const __attribute__((address_space(1))) void*)g,
        (__attribute__((address_space(3))) void*)(slab + w * 1024 + r * 8192), 16, 0, 0);
  }
}

template<int G>
DI void mma16(f32x4 (&acc)[8][4], const bf16x8 (&a)[4], const bf16x8 (&b)[4]){
  __builtin_amdgcn_s_setprio(1);
  #pragma unroll
  for(int i = 0; i < 4; ++i)
    #pragma unroll
    for(int j = 0; j < 4; ++j)
      acc[G * 4 + i][j] =
          __builtin_amdgcn_mfma_f32_16x16x32_bf16(a[i], b[j], acc[G * 4 + i][j], 0, 0, 0);
  __builtin_amdgcn_s_setprio(0);
}
template<int G>
DI void rdA(bf16x8 (&a)[4], const char* LA, int sbase, const int (&offA)[8]){
  #pragma unroll
  for(int i = 0; i < 4; ++i) a[i] = *(const bf16x8*)(LA + sbase + offA[G * 4 + i]);
}
DI void rdB(bf16x8 (&b)[4], const char* LB, int sbase, const int (&offB)[4]){
  #pragma unroll
  for(int j = 0; j < 4; ++j) b[j] = *(const bf16x8*)(LB + sbase + offB[j]);
}
#define VMW(N) asm volatile("s_waitcnt vmcnt(" #N ")" ::: "memory")

// BM=BN=256, BK=64, 8 waves (2Mx4N, wave tile 128x64). nt must be even.
// Unit = kk-slab (256x32, 2 loads/thread). Issue->consume gap 5-6 phases;
// barriers at odd phases only; vmcnt(8) counted (never 0 mid-loop).
// Per-iteration issue stream: A11,B11 | A00,B00 | A01,B01 | A10,B10 — each
// VMW(8) completes exactly the 2 units consumed in the following phase-pair.
template<class FA, class FB>
DI void kloop8(FA fa, long lda, FB fb, long ldb, int nt, int tid,
               char* L, f32x4 (&acc)[8][4]){
  const int lane = tid & 63, w = tid >> 6;
  int offA[8], offB[4];
  #pragma unroll
  for(int i = 0; i < 8; ++i){
    const int r = (w >> 2) * 128 + i * 16 + (lane & 15);
    offA[i] = r * 64 + ((((lane >> 4)) ^ ((r >> 1) & 3)) << 4);
  }
  #pragma unroll
  for(int j = 0; j < 4; ++j){
    const int r = (w & 3) * 64 + j * 16 + (lane & 15);
    offB[j] = r * 64 + ((((lane >> 4)) ^ ((r >> 1) & 3)) << 4);
  }
  char* LA = L;
  char* LB = L + 65536;
  auto AS = [](int s, int k){ return s * 32768 + k * 16384; };
  // prologue: 6 units = 12 loads/thread
  issue_unit(fa(0),      lda, LA + AS(0, 0), tid);
  issue_unit(fb(0),      ldb, LB + AS(0, 0), tid);
  issue_unit(fa(0) + 32, lda, LA + AS(0, 1), tid);
  issue_unit(fb(0) + 32, ldb, LB + AS(0, 1), tid);
  issue_unit(fa(1),      lda, LA + AS(1, 0), tid);
  issue_unit(fb(1),      ldb, LB + AS(1, 0), tid);
  bf16x8 a[4], b[4];
  for(int t = 0; t < nt; t += 2){
    const bool more = (t + 2 < nt);
    // ---- tile t (slot 0) ----
    VMW(8); __builtin_amdgcn_s_barrier();                       // ph1
    issue_unit(fa(t + 1) + 32, lda, LA + AS(1, 1), tid);
    rdB(b, LB, AS(0, 0), offB);
    rdA<0>(a, LA, AS(0, 0), offA);  mma16<0>(acc, a, b);
    issue_unit(fb(t + 1) + 32, ldb, LB + AS(1, 1), tid);        // ph2
    rdA<1>(a, LA, AS(0, 0), offA);  mma16<1>(acc, a, b);
    VMW(8); __builtin_amdgcn_s_barrier();                       // ph3
    if(more) issue_unit(fa(t + 2), lda, LA + AS(0, 0), tid);
    rdB(b, LB, AS(0, 1), offB);
    rdA<0>(a, LA, AS(0, 1), offA);  mma16<0>(acc, a, b);
    if(more) issue_unit(fb(t + 2), ldb, LB + AS(0, 0), tid);    // ph4
    rdA<1>(a, LA, AS(0, 1), offA);  mma16<1>(acc, a, b);
    // ---- tile t+1 (slot 1) ----
    if(more){ VMW(8); } else { VMW(4); }                        // ph5
    __builtin_amdgcn_s_barrier();
    if(more) issue_unit(fa(t + 2) + 32, lda, LA + AS(0, 1), tid);
    rdB(b, LB, AS(1, 0), offB);
    rdA<0>(a, LA, AS(1, 0), offA);  mma16<0>(acc, a, b);
    if(more) issue_unit(fb(t + 2) + 32, ldb, LB + AS(0, 1), tid); // ph6
    rdA<1>(a, LA, AS(1, 0), offA);  mma16<1>(acc, a, b);
    if(more){ VMW(8); } else { VMW(0); }                        // ph7
    __builtin_amdgcn_s_barrier();
    if(more) issue_unit(fa(t + 3), lda, LA + AS(1, 0), tid);
    rdB(b, LB, AS(1, 1), offB);
    rdA<0>(a, LA, AS(1, 1), offA);  mma16<0>(acc, a, b);
    if(more) issue_unit(fb(t + 3), ldb, LB + AS(1, 0), tid);    // ph8
    rdA<1>(a, LA, AS(1, 1), offA);  mma16<1>(acc, a, b);
  }
}

// bijective XCD swizzle (grid divisible by 8)
DI int xcd_swz(int bid, int n){ const int c = n >> 3; return (bid & 7) * c + (bid >> 3); }

// ---------------- fused Q/K/V projections: 256^2 8-phase ----------------
__global__ __launch_bounds__(512, 2)
void proj_qkv(const __bf16* __restrict__ xq, const __bf16* __restrict__ xk,
              const __bf16* __restrict__ xv, const __bf16* __restrict__ Wqb,
              const __bf16* __restrict__ Wkb, const __bf16* __restrict__ Wvb,
              const float* __restrict__ bq, const float* __restrict__ bk,
              const float* __restrict__ bv, __bf16* __restrict__ qb,
              __bf16* __restrict__ kb, __bf16* __restrict__ vbT){
  __shared__ __attribute__((aligned(128))) char L[131072];
  const int z = blockIdx.y, tid = threadIdx.x;
  const int bid = xcd_swz(blockIdx.x, 192);
  const __bf16 *A, *B; const float* bias; __bf16* C;
  long m0, n0, ldc; bool biasm;
  if(z == 0){ A = xq;  B = Wqb; bias = bq; C = qb;
              m0 = (long)(bid / 3) * 256; n0 = (bid % 3) * 256; ldc = DIM; biasm = false; }
  else if(z == 1){ A = xk;  B = Wkb; bias = bk; C = kb;
              m0 = (long)(bid / 3) * 256; n0 = (bid % 3) * 256; ldc = DIM; biasm = false; }
  else {      A = Wvb; B = xv;  bias = bv; C = vbT;
              m0 = (long)(bid / 64) * 256; n0 = (bid % 64) * 256; ldc = TOK; biasm = true; }
  const __bf16* Ar = A + m0 * DIM;
  const __bf16* Br = B + n0 * DIM;
  f32x4 acc[8][4] = {};
  auto fa = [&](int t){ return Ar + t * 64; };
  auto fb = [&](int t){ return Br + t * 64; };
  kloop8(fa, DIM, fb, DIM, DIM / 64, tid, L, acc);

  const int lane = tid & 63, w = tid >> 6;
  const int cl = lane & 15, rq = (lane >> 4) * 4;
  #pragma unroll
  for(int i = 0; i < 8; ++i)
    #pragma unroll
    for(int j = 0; j < 4; ++j){
      const long gc = n0 + (w & 3) * 64 + j * 16 + cl;
      #pragma unroll
      for(int e = 0; e < 4; ++e){
        const long gr = m0 + (w >> 2) * 128 + i * 16 + rq + e;
        C[gr * ldc + gc] = (__bf16)(acc[i][j][e] + bias[biasm ? gr : gc]);
      }
    }
}

// ---------------- QK^T: 256x256 causal tiles, 8-phase, fused exp ----------------
__global__ __launch_bounds__(512, 2)
void qk_kernel(const __bf16* __restrict__ qb, const __bf16* __restrict__ kb,
               __bf16* __restrict__ Pc){
  __shared__ __attribute__((aligned(128))) char L[131072];
  const int b = blockIdx.y, tid = threadIdx.x;
  const int t = xcd_swz(blockIdx.x, 136);             // 0..135 tri tile id
  int Qi = (int)((sqrtf(8.0f * t + 1.0f) - 1.0f) * 0.5f);
  while((Qi + 1) * (Qi + 2) / 2 <= t) Qi++;
  while(Qi * (Qi + 1) / 2 > t) Qi--;
  const int Ki = t - Qi * (Qi + 1) / 2;
  const __bf16* Aq = qb + ((long)b * SEQ + Qi * 256) * DIM;
  const __bf16* Bk = kb + ((long)b * SEQ + Ki * 256) * DIM;
  f32x4 acc[8][4] = {};
  auto fa = [&](int t_){ return Aq + t_ * 64; };
  auto fb = [&](int t_){ return Bk + t_ * 64; };
  kloop8(fa, DIM, fb, DIM, DIM / 64, tid, L, acc);

  const int lane = tid & 63, w = tid >> 6;
  const int cl = lane & 15, rq = (lane >> 4) * 4;
  const int qi = 2 * Qi + (w >> 2);                   // wave's 128-row strip
  #pragma unroll
  for(int j = 0; j < 4; ++j){
    const int kw = (w & 3) * 64 + j * 16;
    const int ki = 2 * Ki + (kw >> 7);
    if(ki > qi) continue;                             // fully-masked subtile
    const bool diag = (ki == qi);
    __bf16* tile = Pc + ((long)b * NTRI + (long)qi * (qi + 1) / 2 + ki) * 16384;
    const int kcol = (kw & 127) + cl;
    #pragma unroll
    for(int i = 0; i < 8; ++i){
      #pragma unroll
      for(int e = 0; e < 4; ++e){
        const int rloc = i * 16 + rq + e;
        float p = (diag && kcol > rloc) ? 0.0f
                  : __expf(fminf(acc[i][j][e] * SCALE, 30.0f));
        tile[rloc * 128 + kcol] = (__bf16)p;
      }
    }
  }
}

// ---------------- per-row 1/sum over compact bf16 P ----------------
__global__ void rowsum(const __bf16* __restrict__ Pc, float* __restrict__ rlrow){
  const int gr = blockIdx.x * 4 + (threadIdx.x >> 6);   // one wave per row
  const int lane = threadIdx.x & 63;
  const int b = gr >> 12, r = gr & 4095;
  const int qi = r >> 7, rloc = r & 127;
  const __bf16* base = Pc + ((long)b * NTRI + (long)qi * (qi + 1) / 2) * 16384
                       + rloc * 128;
  float s = 0.f;
  for(int ki = 0; ki <= qi; ++ki){
    uint32_t u = *(const uint32_t*)(base + (long)ki * 16384 + lane * 2);
    s += __uint_as_float(u << 16) + __uint_as_float(u & 0xffff0000u);
  }
  #pragma unroll
  for(int off = 32; off; off >>= 1) s += __shfl_xor(s, off);
  if(lane == 0) rlrow[gr] = 1.0f / s;
}

// ---------------- P.V: pure 128x256 GEMM over compact P, scaled by 1/l ------------
__global__ __launch_bounds__(512)
void pv_kernel(const __bf16* __restrict__ Pc, const float* __restrict__ rlrow,
               const __bf16* __restrict__ vbT, __bf16* __restrict__ att){
  __shared__ __attribute__((aligned(128))) char As[16384];
  __shared__ __attribute__((aligned(128))) char Bs[32768];
  __shared__ float sRl[128];
  const int b = blockIdx.z, qi = 31 - blockIdx.y, tid = threadIdx.x;  // long-K first
  const long n0 = (long)blockIdx.x * 256;
  if(tid < 128) sRl[tid] = rlrow[b * SEQ + qi * 128 + tid];
  const __bf16* Pq = Pc + ((long)b * NTRI + (long)qi * (qi + 1) / 2) * 16384;
  const __bf16* Bv = vbT + n0 * TOK + (long)b * SEQ;
  f32x4 acc[4][4] = {};
  auto fa = [&](int t){ return Pq + (long)(t >> 1) * 16384 + (t & 1) * 64; };
  auto fb = [&](int t){ return Bv + t * 64; };
  kloop2(fa, 128, fb, TOK, 2 * (qi + 1), tid, As, Bs, acc);   // barriers inside cover sRl

  const int lane = tid & 63, w = tid >> 6;
  const int wr = (w >> 2) * 64, wc = (w & 3) * 64;
  const int cl = lane & 15, rq = (lane >> 4) * 4;
  #pragma unroll
  for(int i = 0; i < 4; ++i)
    #pragma unroll
    for(int j = 0; j < 4; ++j){
      const long gc = n0 + wc + j * 16 + cl;
      #pragma unroll
      for(int e = 0; e < 4; ++e){
        const int rloc = wr + i * 16 + rq + e;
        float v = acc[i][j][e] * sRl[rloc];
        att[((long)b * SEQ + qi * 128 + rloc) * DIM + gc] = (__bf16)v;
      }
    }
}

// ---------------- output projection (round-2 core) -> fp32 d_out ----------------
__global__ __launch_bounds__(512)
void oproj(const __bf16* __restrict__ att, const __bf16* __restrict__ Wob,
           const float* __restrict__ bo, float* __restrict__ out){
  __shared__ __attribute__((aligned(128))) char As[16384];
  __shared__ __attribute__((aligned(128))) char Bs[32768];
  const int bid = blockIdx.x, tid = threadIdx.x;
  const long n0 = (bid % 3) * 256, m0 = (long)(bid / 3) * 128;
  const __bf16* Ar = att + m0 * DIM;
  const __bf16* Br = Wob + n0 * DIM;
  f32x4 acc[4][4] = {};
  auto fa = [&](int t){ return Ar + t * 64; };
  auto fb = [&](int t){ return Br + t * 64; };
  kloop2(fa, DIM, fb, DIM, DIM / 64, tid, As, Bs, acc);
  const int lane = tid & 63, w = tid >> 6;
  const int wr = (w >> 2) * 64, wc = (w & 3) * 64;
  const int cl = lane & 15, rq = (lane >> 4) * 4;
  #pragma unroll
  for(int i = 0; i < 4; ++i)
    #pragma unroll
    for(int j = 0; j < 4; ++j){
      const long gc = n0 + wc + j * 16 + cl;
      #pragma unroll
      for(int e = 0; e < 4; ++e){
        const long gr = m0 + wr + i * 16 + rq + e;
        out[gr * DIM + gc] = acc[i][j][e] + bo[gc];
      }
    }
}

// ---------------- launch ----------------
extern "C" void kernel_launch(void* const* d_in, const int* in_sizes, int n_in,
                              void* d_out, int out_size, void* d_ws, size_t ws_size,
                              hipStream_t stream){
  const float* query = (const float*)d_in[0];
  const float* key_  = (const float*)d_in[1];
  const float* value = (const float*)d_in[2];
  const float* Wq = (const float*)d_in[3];
  const float* bq = (const float*)d_in[4];
  const float* Wk = (const float*)d_in[5];
  const float* bk = (const float*)d_in[6];
  const float* Wv = (const float*)d_in[7];
  const float* bv = (const float*)d_in[8];
  const float* Wo = (const float*)d_in[9];
  const float* bo = (const float*)d_in[10];
  // d_in[11]: causal tril mask — implemented structurally (block-triangular P).

  char* p = (char*)d_ws;
  auto carve = [&](size_t bytes)->char*{
    char* r = p; p += (bytes + 255) & ~(size_t)255; return r;
  };
  const size_t tb = (size_t)TOK * DIM * 2;   // 25.2 MB
  __bf16* xq  = (__bf16*)carve(tb);
  __bf16* xk  = (__bf16*)carve(tb);
  __bf16* xv  = (__bf16*)carve(tb);
  __bf16* qb  = (__bf16*)carve(tb);
  __bf16* kb  = (__bf16*)carve(tb);
  __bf16* vbT = (__bf16*)carve(tb);
  __bf16* Wqb = (__bf16*)carve((size_t)DIM * DIM * 2);
  __bf16* Wkb = (__bf16*)carve((size_t)DIM * DIM * 2);
  __bf16* Wvb = (__bf16*)carve((size_t)DIM * DIM * 2);
  __bf16* Wob = (__bf16*)carve((size_t)DIM * DIM * 2);
  __bf16* Pc  = (__bf16*)carve((size_t)BATCH * NTRI * 16384 * 2);  // 69.2 MB
  float*  rlr = (float*)carve((size_t)TOK * 4);
  __bf16* att = xq;                           // xq dead after q-projection
  if((size_t)(p - (char*)d_ws) > ws_size) return;

  const long nIn4 = TOK * DIM / 4, nW4 = (long)DIM * DIM / 4;
  dim3 g3(2048, 3), g4((unsigned)((nW4 + 255) / 256), 4);
  cvt3_kernel<<<g3, 256, 0, stream>>>(query, key_, value, xq, xk, xv, nIn4);
  cvt4_kernel<<<g4, 256, 0, stream>>>(Wq, Wk, Wv, Wo, Wqb, Wkb, Wvb, Wob, nW4);

  // Q, K, V^T projections: 256^2 8-phase, one dispatch (576 blocks)
  proj_qkv<<<dim3(192, 3), 512, 0, stream>>>(xq, xk, xv, Wqb, Wkb, Wvb,
                                             bq, bk, bv, qb, kb, vbT);

  // QK^T: 256^2 causal tiles (136 per batch), 8-phase
  qk_kernel<<<dim3(136, BATCH), 512, 0, stream>>>(qb, kb, Pc);

  rowsum<<<TOK / 4, 256, 0, stream>>>(Pc, rlr);

  pv_kernel<<<dim3(3, QT, BATCH), 512, 0, stream>>>(Pc, rlr, vbT, att);

  oproj<<<384, 512, 0, stream>>>(att, Wob, bo, (float*)d_out);
}

// Round 7
// 321.120 us; speedup vs baseline: 1.2147x; 1.0580x over previous
//
#include <hip/hip_runtime.h>
#include <hip/hip_bf16.h>
#include <stdint.h>

#define DI __device__ __forceinline__

typedef __bf16 bf16x4 __attribute__((ext_vector_type(4)));
typedef __bf16 bf16x8 __attribute__((ext_vector_type(8)));
typedef float  f32x4  __attribute__((ext_vector_type(4)));

static constexpr int  BATCH = 4;
static constexpr int  SEQ   = 4096;
static constexpr int  DIM   = 768;
static constexpr long TOK   = (long)BATCH * SEQ;        // 16384
static constexpr int  QT    = SEQ / 128;                // 32 q-tiles per batch
static constexpr int  NTRI  = QT * (QT + 1) / 2;        // 528 causal 128x128 tiles
static constexpr float SCALE = 0.0360843918243516150f;  // 1/sqrt(768)

// ---------------- fp32 -> bf16 convert (weights only) ----------------
__global__ void cvt4_kernel(const float* __restrict__ a, const float* __restrict__ b,
                            const float* __restrict__ c, const float* __restrict__ d,
                            __bf16* __restrict__ oa, __bf16* __restrict__ ob,
                            __bf16* __restrict__ oc, __bf16* __restrict__ od, long n4){
  const float* in  = blockIdx.y == 0 ? a : blockIdx.y == 1 ? b : blockIdx.y == 2 ? c : d;
  __bf16*      out = blockIdx.y == 0 ? oa : blockIdx.y == 1 ? ob : blockIdx.y == 2 ? oc : od;
  long i = (long)blockIdx.x * blockDim.x + threadIdx.x;
  const long stride = (long)gridDim.x * blockDim.x;
  for(; i < n4; i += stride){
    float4 v = ((const float4*)in)[i];
    bf16x4 o = { (__bf16)v.x, (__bf16)v.y, (__bf16)v.z, (__bf16)v.w };
    ((bf16x4*)out)[i] = o;
  }
}

// ================= proven 2-phase core =================
// LDS tile: [R rows][64 bf16 = 8 chunks of 16B], chunk XOR-swizzled by (row&7).
DI int swz_off(int r, int c){ return (r << 7) + ((c ^ (r & 7)) << 4); }

// bf16 source: global_load_lds, pre-swizzled global source chunk, linear LDS dest.
template<int R>
DI void stage(const __bf16* __restrict__ src, long ld, char* lds, int tid){
  const int w = tid >> 6, l = tid & 63;
  const int rsub = l >> 3;
  const int kc   = (l & 7) ^ rsub;
  const __bf16* g = src + (long)(w * 8 + rsub) * ld + kc * 8;
  char* d = lds + (w << 10);
  #pragma unroll
  for(int i = 0; i < R / 64; ++i){
    __builtin_amdgcn_global_load_lds(
        (const __attribute__((address_space(1))) void*)(g + (long)(i * 64) * ld),
        (__attribute__((address_space(3))) void*)(d + i * 8192), 16, 0, 0);
  }
}

// f32 source: reg-staged (load 2x float4, convert, ds_write_b128) into the SAME
// swizzled layout as stage<R> (source chunk kc -> linear dest chunk l&7).
template<int R>
DI void stage_cvt(const float* __restrict__ src, long ld, char* lds, int tid){
  const int w = tid >> 6, l = tid & 63;
  const int rsub = l >> 3;
  const int kc   = (l & 7) ^ rsub;
  const float* g = src + (long)(w * 8 + rsub) * ld + kc * 8;
  char* d = lds + (w << 10) + ((l & 63) << 4);
  #pragma unroll
  for(int i = 0; i < R / 64; ++i){
    const float4* s = (const float4*)(g + (long)(i * 64) * ld);
    float4 v0 = s[0], v1 = s[1];
    bf16x8 o = { (__bf16)v0.x, (__bf16)v0.y, (__bf16)v0.z, (__bf16)v0.w,
                 (__bf16)v1.x, (__bf16)v1.y, (__bf16)v1.z, (__bf16)v1.w };
    *(bf16x8*)(d + i * 8192) = o;
  }
}

DI bf16x8 frag_ld(const char* lds, int row, int c){
  return *(const bf16x8*)(lds + swz_off(row, c));
}

// One K=64 step: 32 MFMAs per wave (4x4 frags x 2 k-halves).
DI void mma_tile(const char* As, const char* Bs, int lane, int wr, int wc, f32x4 acc[4][4]){
  #pragma unroll
  for(int kk = 0; kk < 2; ++kk){
    const int c = kk * 4 + (lane >> 4);
    bf16x8 a[4], b[4];
    #pragma unroll
    for(int i = 0; i < 4; ++i) a[i] = frag_ld(As, wr + i * 16 + (lane & 15), c);
    #pragma unroll
    for(int j = 0; j < 4; ++j) b[j] = frag_ld(Bs, wc + j * 16 + (lane & 15), c);
    #pragma unroll
    for(int i = 0; i < 4; ++i)
      #pragma unroll
      for(int j = 0; j < 4; ++j)
        acc[i][j] = __builtin_amdgcn_mfma_f32_16x16x32_bf16(a[i], b[j], acc[i][j], 0, 0, 0);
  }
}

// Single-buffered 128x256 K-loop (48KB LDS -> 3 blocks/CU), all-bf16 operands.
template<class FA, class FB>
DI void kloop2(FA fa, long lda, FB fb, long ldb, int nt, int tid,
               char* As, char* Bs, f32x4 acc[4][4]){
  const int lane = tid & 63, w = tid >> 6;
  const int wr = (w >> 2) * 64, wc = (w & 3) * 64;
  for(int t = 0; t < nt; ++t){
    stage<128>(fa(t), lda, As, tid);
    stage<256>(fb(t), ldb, Bs, tid);
    __syncthreads();
    mma_tile(As, Bs, lane, wr, wc, acc);
    __syncthreads();
  }
}

// ---------------- Q/K projections: A = f32 input (reg-staged), B = bf16 W ------
__global__ __launch_bounds__(512)
void proj_qk(const float* __restrict__ query, const float* __restrict__ key_,
             const __bf16* __restrict__ Wqb, const __bf16* __restrict__ Wkb,
             const float* __restrict__ bq, const float* __restrict__ bk,
             __bf16* __restrict__ qb, __bf16* __restrict__ kb){
  __shared__ __attribute__((aligned(128))) char As[16384];
  __shared__ __attribute__((aligned(128))) char Bs[32768];
  const int z = blockIdx.y, bid = blockIdx.x, tid = threadIdx.x;
  const float*  X = z ? key_ : query;
  const __bf16* W = z ? Wkb : Wqb;
  const float*  bias = z ? bk : bq;
  __bf16*       C = z ? kb : qb;
  const long m0 = (long)(bid / 3) * 128, n0 = (bid % 3) * 256;
  const float*  Ar = X + m0 * DIM;
  const __bf16* Br = W + n0 * DIM;
  f32x4 acc[4][4] = {};
  const int lane = tid & 63, w = tid >> 6;
  const int wr = (w >> 2) * 64, wc = (w & 3) * 64;
  for(int t = 0; t < DIM / 64; ++t){
    stage_cvt<128>(Ar + t * 64, DIM, As, tid);
    stage<256>(Br + t * 64, DIM, Bs, tid);
    __syncthreads();
    mma_tile(As, Bs, lane, wr, wc, acc);
    __syncthreads();
  }
  const int cl = lane & 15, rq = (lane >> 4) * 4;
  #pragma unroll
  for(int i = 0; i < 4; ++i)
    #pragma unroll
    for(int j = 0; j < 4; ++j){
      const long gc = n0 + wc + j * 16 + cl;
      #pragma unroll
      for(int e = 0; e < 4; ++e){
        const long gr = m0 + wr + i * 16 + rq + e;
        C[gr * DIM + gc] = (__bf16)(acc[i][j][e] + bias[gc]);
      }
    }
}

// ---------------- V^T projection: A = bf16 Wv, B = f32 value (reg-staged) ------
__global__ __launch_bounds__(512)
void proj_vT(const __bf16* __restrict__ Wvb, const float* __restrict__ value,
             const float* __restrict__ bv, __bf16* __restrict__ vbT){
  __shared__ __attribute__((aligned(128))) char As[16384];
  __shared__ __attribute__((aligned(128))) char Bs[32768];
  const int bid = blockIdx.x, tid = threadIdx.x;
  const long m0 = (long)(bid / 64) * 128, n0 = (long)(bid % 64) * 256;
  const __bf16* Ar = Wvb + m0 * DIM;
  const float*  Br = value + n0 * DIM;
  f32x4 acc[4][4] = {};
  const int lane = tid & 63, w = tid >> 6;
  const int wr = (w >> 2) * 64, wc = (w & 3) * 64;
  for(int t = 0; t < DIM / 64; ++t){
    stage<128>(Ar + t * 64, DIM, As, tid);
    stage_cvt<256>(Br + t * 64, DIM, Bs, tid);
    __syncthreads();
    mma_tile(As, Bs, lane, wr, wc, acc);
    __syncthreads();
  }
  const int cl = lane & 15, rq = (lane >> 4) * 4;
  #pragma unroll
  for(int i = 0; i < 4; ++i)
    #pragma unroll
    for(int j = 0; j < 4; ++j){
      const long gc = n0 + wc + j * 16 + cl;
      #pragma unroll
      for(int e = 0; e < 4; ++e){
        const long gr = m0 + wr + i * 16 + rq + e;
        vbT[gr * TOK + gc] = (__bf16)(acc[i][j][e] + bv[gr]);
      }
    }
}

// ---------------- QK^T: 2-phase 256q x 128k, fused exp + atomic row-sums --------
__global__ __launch_bounds__(512)
void qk_kernel(const __bf16* __restrict__ qb, const __bf16* __restrict__ kb,
               __bf16* __restrict__ Pc, float* __restrict__ rlsum){
  const int b = blockIdx.y, t2 = blockIdx.x, tid = threadIdx.x;
  // decode t2 -> (Qi 256-row tile, ki 128-col tile), ki <= 2*Qi+1
  int Qi = (int)((sqrtf(4.0f * t2 + 1.0f) - 1.0f) * 0.5f);
  while((Qi + 1) * (Qi + 2) <= t2) Qi++;
  while(Qi * (Qi + 1) > t2) Qi--;
  const int ki = t2 - Qi * (Qi + 1);
  const __bf16* Aq = qb + ((long)b * SEQ + Qi * 256) * DIM;
  const __bf16* Bk = kb + ((long)b * SEQ + ki * 128) * DIM;
  __shared__ __attribute__((aligned(128))) char As[32768];
  __shared__ __attribute__((aligned(128))) char Bs[16384];
  const int lane = tid & 63, w = tid >> 6;
  const int wr = (w >> 1) * 64, wc = (w & 1) * 64;   // 4M x 2N waves
  f32x4 acc[4][4] = {};
  for(int t = 0; t < DIM / 64; ++t){
    stage<256>(Aq + t * 64, DIM, As, tid);
    stage<128>(Bk + t * 64, DIM, Bs, tid);
    __syncthreads();
    mma_tile(As, Bs, lane, wr, wc, acc);
    __syncthreads();
  }
  const int cl = lane & 15, rq = (lane >> 4) * 4;
  #pragma unroll
  for(int i = 0; i < 4; ++i){
    const int rbase = wr + i * 16;                    // 0..255
    const int qi = 2 * Qi + (rbase >> 7);
    if(ki > qi) continue;                             // fully-masked half-tile
    const bool diag = (ki == qi);
    __bf16* tile = Pc + ((long)b * NTRI + (long)qi * (qi + 1) / 2 + ki) * 16384;
    float rsum[4] = {0.f, 0.f, 0.f, 0.f};
    #pragma unroll
    for(int j = 0; j < 4; ++j){
      const int c = wc + j * 16 + cl;
      #pragma unroll
      for(int e = 0; e < 4; ++e){
        const int rloc = (rbase + rq + e) & 127;
        float p = (diag && c > rloc) ? 0.0f
                  : __expf(fminf(acc[i][j][e] * SCALE, 30.0f));
        tile[rloc * 128 + c] = (__bf16)p;
        rsum[e] += p;
      }
    }
    #pragma unroll
    for(int e = 0; e < 4; ++e){                       // reduce across 16 col-lanes
      float s = rsum[e];
      s += __shfl_xor(s, 1); s += __shfl_xor(s, 2);
      s += __shfl_xor(s, 4); s += __shfl_xor(s, 8);
      if(cl == 0){
        const long gr = (long)b * SEQ + Qi * 256 + rbase + rq + e;
        atomicAdd(&rlsum[gr], s);
      }
    }
  }
}

// ---------------- P.V: pure 128x256 GEMM over compact P, scaled by 1/sum --------
__global__ __launch_bounds__(512)
void pv_kernel(const __bf16* __restrict__ Pc, const float* __restrict__ rlsum,
               const __bf16* __restrict__ vbT, __bf16* __restrict__ att){
  __shared__ __attribute__((aligned(128))) char As[16384];
  __shared__ __attribute__((aligned(128))) char Bs[32768];
  __shared__ float sRl[128];
  const int b = blockIdx.z, qi = 31 - blockIdx.y, tid = threadIdx.x;  // long-K first
  const long n0 = (long)blockIdx.x * 256;
  if(tid < 128) sRl[tid] = 1.0f / rlsum[b * SEQ + qi * 128 + tid];
  const __bf16* Pq = Pc + ((long)b * NTRI + (long)qi * (qi + 1) / 2) * 16384;
  const __bf16* Bv = vbT + n0 * TOK + (long)b * SEQ;
  f32x4 acc[4][4] = {};
  auto fa = [&](int t){ return Pq + (long)(t >> 1) * 16384 + (t & 1) * 64; };
  auto fb = [&](int t){ return Bv + t * 64; };
  kloop2(fa, 128, fb, TOK, 2 * (qi + 1), tid, As, Bs, acc);   // barriers cover sRl

  const int lane = tid & 63, w = tid >> 6;
  const int wr = (w >> 2) * 64, wc = (w & 3) * 64;
  const int cl = lane & 15, rq = (lane >> 4) * 4;
  #pragma unroll
  for(int i = 0; i < 4; ++i)
    #pragma unroll
    for(int j = 0; j < 4; ++j){
      const long gc = n0 + wc + j * 16 + cl;
      #pragma unroll
      for(int e = 0; e < 4; ++e){
        const int rloc = wr + i * 16 + rq + e;
        float v = acc[i][j][e] * sRl[rloc];
        att[((long)b * SEQ + qi * 128 + rloc) * DIM + gc] = (__bf16)v;
      }
    }
}

// ---------------- output projection -> fp32 d_out ----------------
__global__ __launch_bounds__(512)
void oproj(const __bf16* __restrict__ att, const __bf16* __restrict__ Wob,
           const float* __restrict__ bo, float* __restrict__ out){
  __shared__ __attribute__((aligned(128))) char As[16384];
  __shared__ __attribute__((aligned(128))) char Bs[32768];
  const int bid = blockIdx.x, tid = threadIdx.x;
  const long n0 = (bid % 3) * 256, m0 = (long)(bid / 3) * 128;
  const __bf16* Ar = att + m0 * DIM;
  const __bf16* Br = Wob + n0 * DIM;
  f32x4 acc[4][4] = {};
  auto fa = [&](int t){ return Ar + t * 64; };
  auto fb = [&](int t){ return Br + t * 64; };
  kloop2(fa, DIM, fb, DIM, DIM / 64, tid, As, Bs, acc);
  const int lane = tid & 63, w = tid >> 6;
  const int wr = (w >> 2) * 64, wc = (w & 3) * 64;
  const int cl = lane & 15, rq = (lane >> 4) * 4;
  #pragma unroll
  for(int i = 0; i < 4; ++i)
    #pragma unroll
    for(int j = 0; j < 4; ++j){
      const long gc = n0 + wc + j * 16 + cl;
      #pragma unroll
      for(int e = 0; e < 4; ++e){
        const long gr = m0 + wr + i * 16 + rq + e;
        out[gr * DIM + gc] = acc[i][j][e] + bo[gc];
      }
    }
}

// ---------------- launch ----------------
extern "C" void kernel_launch(void* const* d_in, const int* in_sizes, int n_in,
                              void* d_out, int out_size, void* d_ws, size_t ws_size,
                              hipStream_t stream){
  const float* query = (const float*)d_in[0];
  const float* key_  = (const float*)d_in[1];
  const float* value = (const float*)d_in[2];
  const float* Wq = (const float*)d_in[3];
  const float* bq = (const float*)d_in[4];
  const float* Wk = (const float*)d_in[5];
  const float* bk = (const float*)d_in[6];
  const float* Wv = (const float*)d_in[7];
  const float* bv = (const float*)d_in[8];
  const float* Wo = (const float*)d_in[9];
  const float* bo = (const float*)d_in[10];
  // d_in[11]: causal tril mask — implemented structurally (block-triangular P).

  char* p = (char*)d_ws;
  auto carve = [&](size_t bytes)->char*{
    char* r = p; p += (bytes + 255) & ~(size_t)255; return r;
  };
  const size_t tb = (size_t)TOK * DIM * 2;   // 25.2 MB
  __bf16* qb  = (__bf16*)carve(tb);
  __bf16* kb  = (__bf16*)carve(tb);
  __bf16* vbT = (__bf16*)carve(tb);
  __bf16* att = (__bf16*)carve(tb);
  __bf16* Wqb = (__bf16*)carve((size_t)DIM * DIM * 2);
  __bf16* Wkb = (__bf16*)carve((size_t)DIM * DIM * 2);
  __bf16* Wvb = (__bf16*)carve((size_t)DIM * DIM * 2);
  __bf16* Wob = (__bf16*)carve((size_t)DIM * DIM * 2);
  __bf16* Pc  = (__bf16*)carve((size_t)BATCH * NTRI * 16384 * 2);  // 69.2 MB
  float*  rlr = (float*)carve((size_t)TOK * 4);
  if((size_t)(p - (char*)d_ws) > ws_size) return;

  const long nW4 = (long)DIM * DIM / 4;
  dim3 g4((unsigned)((nW4 + 255) / 256), 4);
  hipMemsetAsync(rlr, 0, (size_t)TOK * 4, stream);     // row-sum accumulators
  cvt4_kernel<<<g4, 256, 0, stream>>>(Wq, Wk, Wv, Wo, Wqb, Wkb, Wvb, Wob, nW4);

  // Q, K projections (f32 inputs read directly; cvt fused into staging)
  proj_qk<<<dim3(384, 2), 512, 0, stream>>>(query, key_, Wqb, Wkb, bq, bk, qb, kb);
  // V^T projection
  proj_vT<<<384, 512, 0, stream>>>(Wvb, value, bv, vbT);

  // QK^T with fused exp + row-sum atomics (2-phase, 3 blocks/CU)
  qk_kernel<<<dim3(272, BATCH), 512, 0, stream>>>(qb, kb, Pc, rlr);

  pv_kernel<<<dim3(3, QT, BATCH), 512, 0, stream>>>(Pc, rlr, vbT, att);

  oproj<<<384, 512, 0, stream>>>(att, Wob, bo, (float*)d_out);
}

// Round 8
// 315.749 us; speedup vs baseline: 1.2353x; 1.0170x over previous
//
#include <hip/hip_runtime.h>
#include <hip/hip_bf16.h>
#include <stdint.h>

#define DI __device__ __forceinline__

typedef __bf16 bf16x4 __attribute__((ext_vector_type(4)));
typedef __bf16 bf16x8 __attribute__((ext_vector_type(8)));
typedef float  f32x4  __attribute__((ext_vector_type(4)));

static constexpr int  BATCH = 4;
static constexpr int  SEQ   = 4096;
static constexpr int  DIM   = 768;
static constexpr long TOK   = (long)BATCH * SEQ;        // 16384
static constexpr int  QT    = SEQ / 128;                // 32 q-tiles per batch
static constexpr int  NTRI  = QT * (QT + 1) / 2;        // 528 causal 128x128 tiles
static constexpr float SCALE = 0.0360843918243516150f;  // 1/sqrt(768)

// ---------------- fp32 -> bf16 convert (weights only) ----------------
__global__ void cvt4_kernel(const float* __restrict__ a, const float* __restrict__ b,
                            const float* __restrict__ c, const float* __restrict__ d,
                            __bf16* __restrict__ oa, __bf16* __restrict__ ob,
                            __bf16* __restrict__ oc, __bf16* __restrict__ od, long n4){
  const float* in  = blockIdx.y == 0 ? a : blockIdx.y == 1 ? b : blockIdx.y == 2 ? c : d;
  __bf16*      out = blockIdx.y == 0 ? oa : blockIdx.y == 1 ? ob : blockIdx.y == 2 ? oc : od;
  long i = (long)blockIdx.x * blockDim.x + threadIdx.x;
  const long stride = (long)gridDim.x * blockDim.x;
  for(; i < n4; i += stride){
    float4 v = ((const float4*)in)[i];
    bf16x4 o = { (__bf16)v.x, (__bf16)v.y, (__bf16)v.z, (__bf16)v.w };
    ((bf16x4*)out)[i] = o;
  }
}

// ================= proven 2-phase core =================
// LDS tile: [R rows][64 bf16 = 8 chunks of 16B], chunk XOR-swizzled by (row&7).
DI int swz_off(int r, int c){ return (r << 7) + ((c ^ (r & 7)) << 4); }

// bf16 source: global_load_lds, pre-swizzled global source chunk, linear LDS dest.
template<int R>
DI void stage(const __bf16* __restrict__ src, long ld, char* lds, int tid){
  const int w = tid >> 6, l = tid & 63;
  const int rsub = l >> 3;
  const int kc   = (l & 7) ^ rsub;
  const __bf16* g = src + (long)(w * 8 + rsub) * ld + kc * 8;
  char* d = lds + (w << 10);
  #pragma unroll
  for(int i = 0; i < R / 64; ++i){
    __builtin_amdgcn_global_load_lds(
        (const __attribute__((address_space(1))) void*)(g + (long)(i * 64) * ld),
        (__attribute__((address_space(3))) void*)(d + i * 8192), 16, 0, 0);
  }
}

// f32 source: reg-staged (load 2x float4, convert, ds_write_b128), same layout.
template<int R>
DI void stage_cvt(const float* __restrict__ src, long ld, char* lds, int tid){
  const int w = tid >> 6, l = tid & 63;
  const int rsub = l >> 3;
  const int kc   = (l & 7) ^ rsub;
  const float* g = src + (long)(w * 8 + rsub) * ld + kc * 8;
  char* d = lds + (w << 10) + (l << 4);
  #pragma unroll
  for(int i = 0; i < R / 64; ++i){
    const float4* s = (const float4*)(g + (long)(i * 64) * ld);
    float4 v0 = s[0], v1 = s[1];
    bf16x8 o = { (__bf16)v0.x, (__bf16)v0.y, (__bf16)v0.z, (__bf16)v0.w,
                 (__bf16)v1.x, (__bf16)v1.y, (__bf16)v1.z, (__bf16)v1.w };
    *(bf16x8*)(d + i * 8192) = o;
  }
}

// dual bf16 source, summed (oproj A = att0 + att1), same layout.
template<int R>
DI void stage_add(const __bf16* __restrict__ a0, const __bf16* __restrict__ a1,
                  long ld, char* lds, int tid){
  const int w = tid >> 6, l = tid & 63;
  const int rsub = l >> 3;
  const int kc   = (l & 7) ^ rsub;
  const long off = (long)(w * 8 + rsub) * ld + kc * 8;
  char* d = lds + (w << 10) + (l << 4);
  #pragma unroll
  for(int i = 0; i < R / 64; ++i){
    bf16x8 v0 = *(const bf16x8*)(a0 + off + (long)(i * 64) * ld);
    bf16x8 v1 = *(const bf16x8*)(a1 + off + (long)(i * 64) * ld);
    bf16x8 o;
    #pragma unroll
    for(int e = 0; e < 8; ++e) o[e] = (__bf16)((float)v0[e] + (float)v1[e]);
    *(bf16x8*)(d + i * 8192) = o;
  }
}

DI bf16x8 frag_ld(const char* lds, int row, int c){
  return *(const bf16x8*)(lds + swz_off(row, c));
}

// One K=64 step: 32 MFMAs per wave (4x4 frags x 2 k-halves).
DI void mma_tile(const char* As, const char* Bs, int lane, int wr, int wc, f32x4 acc[4][4]){
  #pragma unroll
  for(int kk = 0; kk < 2; ++kk){
    const int c = kk * 4 + (lane >> 4);
    bf16x8 a[4], b[4];
    #pragma unroll
    for(int i = 0; i < 4; ++i) a[i] = frag_ld(As, wr + i * 16 + (lane & 15), c);
    #pragma unroll
    for(int j = 0; j < 4; ++j) b[j] = frag_ld(Bs, wc + j * 16 + (lane & 15), c);
    #pragma unroll
    for(int i = 0; i < 4; ++i)
      #pragma unroll
      for(int j = 0; j < 4; ++j)
        acc[i][j] = __builtin_amdgcn_mfma_f32_16x16x32_bf16(a[i], b[j], acc[i][j], 0, 0, 0);
  }
}

// Single-buffered 128x256 K-loop (48KB LDS -> 3 blocks/CU), all-bf16 operands.
template<class FA, class FB>
DI void kloop2(FA fa, long lda, FB fb, long ldb, int nt, int tid,
               char* As, char* Bs, f32x4 acc[4][4]){
  const int lane = tid & 63, w = tid >> 6;
  const int wr = (w >> 2) * 64, wc = (w & 3) * 64;
  for(int t = 0; t < nt; ++t){
    stage<128>(fa(t), lda, As, tid);
    stage<256>(fb(t), ldb, Bs, tid);
    __syncthreads();
    mma_tile(As, Bs, lane, wr, wc, acc);
    __syncthreads();
  }
}

// ---------------- fused Q/K/V^T projections (one dispatch, 3x384 blocks) --------
__global__ __launch_bounds__(512)
void proj_qkv(const float* __restrict__ query, const float* __restrict__ key_,
              const float* __restrict__ value, const __bf16* __restrict__ Wqb,
              const __bf16* __restrict__ Wkb, const __bf16* __restrict__ Wvb,
              const float* __restrict__ bq, const float* __restrict__ bk,
              const float* __restrict__ bv, __bf16* __restrict__ qb,
              __bf16* __restrict__ kb, __bf16* __restrict__ vbT){
  __shared__ __attribute__((aligned(128))) char As[16384];
  __shared__ __attribute__((aligned(128))) char Bs[32768];
  const int z = blockIdx.y, bid = blockIdx.x, tid = threadIdx.x;
  const int lane = tid & 63, w = tid >> 6;
  const int wr = (w >> 2) * 64, wc = (w & 3) * 64;
  f32x4 acc[4][4] = {};
  const int cl = lane & 15, rq = (lane >> 4) * 4;

  if(z < 2){                    // Q / K: A = f32 input (reg-staged), B = bf16 W
    const float*  X = z ? key_ : query;
    const __bf16* W = z ? Wkb : Wqb;
    const float*  bias = z ? bk : bq;
    __bf16*       C = z ? kb : qb;
    const long m0 = (long)(bid / 3) * 128, n0 = (bid % 3) * 256;
    const float*  Ar = X + m0 * DIM;
    const __bf16* Br = W + n0 * DIM;
    for(int t = 0; t < DIM / 64; ++t){
      stage_cvt<128>(Ar + t * 64, DIM, As, tid);
      stage<256>(Br + t * 64, DIM, Bs, tid);
      __syncthreads();
      mma_tile(As, Bs, lane, wr, wc, acc);
      __syncthreads();
    }
    #pragma unroll
    for(int i = 0; i < 4; ++i)
      #pragma unroll
      for(int j = 0; j < 4; ++j){
        const long gc = n0 + wc + j * 16 + cl;
        #pragma unroll
        for(int e = 0; e < 4; ++e){
          const long gr = m0 + wr + i * 16 + rq + e;
          C[gr * DIM + gc] = (__bf16)(acc[i][j][e] + bias[gc]);
        }
      }
  } else {                      // V^T: A = bf16 Wv, B = f32 value (reg-staged)
    const long m0 = (long)(bid / 64) * 128, n0 = (long)(bid % 64) * 256;
    const __bf16* Ar = Wvb + m0 * DIM;
    const float*  Br = value + n0 * DIM;
    for(int t = 0; t < DIM / 64; ++t){
      stage<128>(Ar + t * 64, DIM, As, tid);
      stage_cvt<256>(Br + t * 64, DIM, Bs, tid);
      __syncthreads();
      mma_tile(As, Bs, lane, wr, wc, acc);
      __syncthreads();
    }
    #pragma unroll
    for(int i = 0; i < 4; ++i)
      #pragma unroll
      for(int j = 0; j < 4; ++j){
        const long gc = n0 + wc + j * 16 + cl;
        #pragma unroll
        for(int e = 0; e < 4; ++e){
          const long gr = m0 + wr + i * 16 + rq + e;
          vbT[gr * TOK + gc] = (__bf16)(acc[i][j][e] + bv[gr]);
        }
      }
  }
}

// ---------------- QK^T: 2-phase 256q x 128k, fused exp + atomic row-sums --------
__global__ __launch_bounds__(512)
void qk_kernel(const __bf16* __restrict__ qb, const __bf16* __restrict__ kb,
               __bf16* __restrict__ Pc, float* __restrict__ rlsum){
  const int b = blockIdx.y, t2 = blockIdx.x, tid = threadIdx.x;
  int Qi = (int)((sqrtf(4.0f * t2 + 1.0f) - 1.0f) * 0.5f);
  while((Qi + 1) * (Qi + 2) <= t2) Qi++;
  while(Qi * (Qi + 1) > t2) Qi--;
  const int ki = t2 - Qi * (Qi + 1);
  const __bf16* Aq = qb + ((long)b * SEQ + Qi * 256) * DIM;
  const __bf16* Bk = kb + ((long)b * SEQ + ki * 128) * DIM;
  __shared__ __attribute__((aligned(128))) char As[32768];
  __shared__ __attribute__((aligned(128))) char Bs[16384];
  const int lane = tid & 63, w = tid >> 6;
  const int wr = (w >> 1) * 64, wc = (w & 1) * 64;   // 4M x 2N waves
  f32x4 acc[4][4] = {};
  for(int t = 0; t < DIM / 64; ++t){
    stage<256>(Aq + t * 64, DIM, As, tid);
    stage<128>(Bk + t * 64, DIM, Bs, tid);
    __syncthreads();
    mma_tile(As, Bs, lane, wr, wc, acc);
    __syncthreads();
  }
  const int cl = lane & 15, rq = (lane >> 4) * 4;
  #pragma unroll
  for(int i = 0; i < 4; ++i){
    const int rbase = wr + i * 16;                    // 0..255
    const int qi = 2 * Qi + (rbase >> 7);
    if(ki > qi) continue;                             // fully-masked half-tile
    const bool diag = (ki == qi);
    __bf16* tile = Pc + ((long)b * NTRI + (long)qi * (qi + 1) / 2 + ki) * 16384;
    float rsum[4] = {0.f, 0.f, 0.f, 0.f};
    #pragma unroll
    for(int j = 0; j < 4; ++j){
      const int c = wc + j * 16 + cl;
      #pragma unroll
      for(int e = 0; e < 4; ++e){
        const int rloc = (rbase + rq + e) & 127;
        float p = (diag && c > rloc) ? 0.0f
                  : __expf(fminf(acc[i][j][e] * SCALE, 30.0f));
        tile[rloc * 128 + c] = (__bf16)p;
        rsum[e] += p;
      }
    }
    #pragma unroll
    for(int e = 0; e < 4; ++e){                       // reduce across 16 col-lanes
      float s = rsum[e];
      s += __shfl_xor(s, 1); s += __shfl_xor(s, 2);
      s += __shfl_xor(s, 4); s += __shfl_xor(s, 8);
      if(cl == 0){
        const long gr = (long)b * SEQ + Qi * 256 + rbase + rq + e;
        atomicAdd(&rlsum[gr], s);
      }
    }
  }
}

// ---------------- P.V: K-split 128x256 GEMM, partials to att0/att1 ----------
// grid: x = 12 (n-tile*4 + batch), y = 63 (balanced 2-way K-split, long-first).
__global__ __launch_bounds__(512)
void pv_kernel(const __bf16* __restrict__ Pc, const float* __restrict__ rlsum,
               const __bf16* __restrict__ vbT, __bf16* __restrict__ att0,
               __bf16* __restrict__ att1){
  __shared__ __attribute__((aligned(128))) char As[16384];
  __shared__ __attribute__((aligned(128))) char Bs[32768];
  __shared__ float sRl[128];
  const int x = blockIdx.x, y = blockIdx.y, tid = threadIdx.x;
  const long n0 = (long)(x >> 2) * 256;
  const int b = x & 3;
  int qi, k0, k1, half;
  if(y == 62){ qi = 0; k0 = 0; k1 = 1; half = 0; }
  else{
    qi = 31 - (y >> 1); half = y & 1;
    const int c0 = (qi + 2) >> 1;
    if(half == 0){ k0 = 0; k1 = c0; } else { k0 = c0; k1 = qi + 1; }
  }
  if(tid < 128) sRl[tid] = 1.0f / rlsum[b * SEQ + qi * 128 + tid];
  const __bf16* Pq = Pc + ((long)b * NTRI + (long)qi * (qi + 1) / 2) * 16384;
  const __bf16* Bv = vbT + n0 * TOK + (long)b * SEQ;
  f32x4 acc[4][4] = {};
  auto fa = [&](int t){ return Pq + (long)(k0 + (t >> 1)) * 16384 + (t & 1) * 64; };
  auto fb = [&](int t){ return Bv + (long)k0 * 128 + t * 64; };
  kloop2(fa, 128, fb, TOK, 2 * (k1 - k0), tid, As, Bs, acc);  // barriers cover sRl

  __bf16* dst = half ? att1 : att0;
  const int lane = tid & 63, w = tid >> 6;
  const int wr = (w >> 2) * 64, wc = (w & 3) * 64;
  const int cl = lane & 15, rq = (lane >> 4) * 4;
  #pragma unroll
  for(int i = 0; i < 4; ++i)
    #pragma unroll
    for(int j = 0; j < 4; ++j){
      const long gc = n0 + wc + j * 16 + cl;
      #pragma unroll
      for(int e = 0; e < 4; ++e){
        const int rloc = wr + i * 16 + rq + e;
        float v = acc[i][j][e] * sRl[rloc];
        dst[((long)b * SEQ + qi * 128 + rloc) * DIM + gc] = (__bf16)v;
      }
    }
}

// ---------------- output projection: A = att0+att1 (fused add) -> fp32 ----------
__global__ __launch_bounds__(512)
void oproj(const __bf16* __restrict__ att0, const __bf16* __restrict__ att1,
           const __bf16* __restrict__ Wob, const float* __restrict__ bo,
           float* __restrict__ out){
  __shared__ __attribute__((aligned(128))) char As[16384];
  __shared__ __attribute__((aligned(128))) char Bs[32768];
  const int bid = blockIdx.x, tid = threadIdx.x;
  const long n0 = (bid % 3) * 256, m0 = (long)(bid / 3) * 128;
  const __bf16* Br = Wob + n0 * DIM;
  f32x4 acc[4][4] = {};
  const int lane = tid & 63, w = tid >> 6;
  const int wr = (w >> 2) * 64, wc = (w & 3) * 64;
  for(int t = 0; t < DIM / 64; ++t){
    stage_add<128>(att0 + m0 * DIM + t * 64, att1 + m0 * DIM + t * 64, DIM, As, tid);
    stage<256>(Br + t * 64, DIM, Bs, tid);
    __syncthreads();
    mma_tile(As, Bs, lane, wr, wc, acc);
    __syncthreads();
  }
  const int cl = lane & 15, rq = (lane >> 4) * 4;
  #pragma unroll
  for(int i = 0; i < 4; ++i)
    #pragma unroll
    for(int j = 0; j < 4; ++j){
      const long gc = n0 + wc + j * 16 + cl;
      #pragma unroll
      for(int e = 0; e < 4; ++e){
        const long gr = m0 + wr + i * 16 + rq + e;
        out[gr * DIM + gc] = acc[i][j][e] + bo[gc];
      }
    }
}

// ---------------- launch ----------------
extern "C" void kernel_launch(void* const* d_in, const int* in_sizes, int n_in,
                              void* d_out, int out_size, void* d_ws, size_t ws_size,
                              hipStream_t stream){
  const float* query = (const float*)d_in[0];
  const float* key_  = (const float*)d_in[1];
  const float* value = (const float*)d_in[2];
  const float* Wq = (const float*)d_in[3];
  const float* bq = (const float*)d_in[4];
  const float* Wk = (const float*)d_in[5];
  const float* bk = (const float*)d_in[6];
  const float* Wv = (const float*)d_in[7];
  const float* bv = (const float*)d_in[8];
  const float* Wo = (const float*)d_in[9];
  const float* bo = (const float*)d_in[10];
  // d_in[11]: causal tril mask — implemented structurally (block-triangular P).

  char* p = (char*)d_ws;
  auto carve = [&](size_t bytes)->char*{
    char* r = p; p += (bytes + 255) & ~(size_t)255; return r;
  };
  const size_t tb = (size_t)TOK * DIM * 2;   // 25.2 MB
  __bf16* qb   = (__bf16*)carve(tb);
  __bf16* kb   = (__bf16*)carve(tb);
  __bf16* vbT  = (__bf16*)carve(tb);
  __bf16* att0 = (__bf16*)carve(tb);
  __bf16* att1 = (__bf16*)carve(tb);
  __bf16* Wqb = (__bf16*)carve((size_t)DIM * DIM * 2);
  __bf16* Wkb = (__bf16*)carve((size_t)DIM * DIM * 2);
  __bf16* Wvb = (__bf16*)carve((size_t)DIM * DIM * 2);
  __bf16* Wob = (__bf16*)carve((size_t)DIM * DIM * 2);
  __bf16* Pc  = (__bf16*)carve((size_t)BATCH * NTRI * 16384 * 2);  // 69.2 MB
  float*  rlr = (float*)carve((size_t)TOK * 4);
  if((size_t)(p - (char*)d_ws) > ws_size) return;

  const long nW4 = (long)DIM * DIM / 4;
  dim3 g4((unsigned)((nW4 + 255) / 256), 4);
  hipMemsetAsync(rlr, 0, (size_t)TOK * 4, stream);     // row-sum accumulators
  hipMemsetAsync(att1, 0, tb, stream);                 // second K-split partial
  cvt4_kernel<<<g4, 256, 0, stream>>>(Wq, Wk, Wv, Wo, Wqb, Wkb, Wvb, Wob, nW4);

  // Q, K, V^T projections in one dispatch (f32 inputs, cvt fused into staging)
  proj_qkv<<<dim3(384, 3), 512, 0, stream>>>(query, key_, value, Wqb, Wkb, Wvb,
                                             bq, bk, bv, qb, kb, vbT);

  // QK^T with fused exp + row-sum atomics (2-phase, 3 blocks/CU)
  qk_kernel<<<dim3(272, BATCH), 512, 0, stream>>>(qb, kb, Pc, rlr);

  // P.V with balanced 2-way K-split (756 blocks, longest chunks first)
  pv_kernel<<<dim3(12, 63), 512, 0, stream>>>(Pc, rlr, vbT, att0, att1);

  // output projection, att0+att1 fused into A-staging -> fp32 d_out
  oproj<<<384, 512, 0, stream>>>(att0, att1, Wob, bo, (float*)d_out);
}